// Round 7
// baseline (2040.984 us; speedup 1.0000x reference)
//
#include <hip/hip_runtime.h>
#include <hip/hip_bf16.h>
#include <cmath>

// ---------------------------------------------------------------------------
// MoE "pure field": gate(softmax@T=e, top-5/8, renorm, sign) + dense 2-layer
// FFN over all experts, accumulated with signed gate weights.
//   N=8192, D_IN=1024, D_HID=4096, D_OUT=1024, E=8, k=5
// Round 10: top-k sparsity exploitation (37.5% FLOP cut). The gate keeps
//   exactly 5/8 experts per row; dropped experts contribute EXACT zeros.
//   Per-expert compacted row lists (gate scatters via atomicAdd); GEMM1
//   gathers A-rows in staging, writes compact hh; GEMM2 runs on compact hh
//   and scatters its epilogue through idx. GEMM schedule = R4-proven
//   (256x256 BK=64, 4 phases, vmcnt(6) ledger, swizzle) — untouched.
//   R6's DS-pipeline regressed and is reverted.
// ---------------------------------------------------------------------------

typedef _Float16 f16;
typedef _Float16 f16x8 __attribute__((ext_vector_type(8)));
typedef _Float16 f16x4 __attribute__((ext_vector_type(4)));
typedef float f32x4 __attribute__((ext_vector_type(4)));

#define NROWS 8192
#define DIN   1024
#define DHID  4096
#define DOUT  1024
#define NEXP  8

// workspace layout (bytes)
#define OFF_SGATE 0u            // sgate: 8192x8 f32 = 256KB
#define OFF_CNT   262144u       // cnt: 8 ints (+pad 4KB)
#define OFF_IDX   266240u       // idx: 8 x 8192 ints = 256KB
#define OFF_XH    528384u       // xh: 8192x1024 f16 = 16MB
#define OFF_W1T   17305600u     // w1t: 8x4096x1024 f16 = 64MB
#define OFF_W2T   84414464u     // w2t: 8x1024x4096 f16 = 64MB
#define OFF_P1    151523328u    // P1 partial f32 = 32MB
#define OFF_HH    185077760u    // hh compact: 8192x4096 f16 = 64MB
// total ~240MB; harness provides >=722MB (NE8 tier fired in round 3)

__device__ __forceinline__ void gload_lds16(const void* gsrc, void* ldsdst) {
  __builtin_amdgcn_global_load_lds(
      (const __attribute__((address_space(1))) unsigned int*)gsrc,
      (__attribute__((address_space(3))) unsigned int*)ldsdst, 16, 0, 0);
}

// zero out (8M f32) + P1 (8M f32) + cnt. Must run before gate / GEMM2.
__global__ void zero_init(float* __restrict__ out, float* __restrict__ p1,
                          int* __restrict__ cnt) {
  const size_t i = (size_t)blockIdx.x * 256 + threadIdx.x;
  const float4 z = make_float4(0.f, 0.f, 0.f, 0.f);
  ((float4*)out)[i] = z;
  ((float4*)p1)[i] = z;
  if (blockIdx.x == 0 && threadIdx.x < 8) cnt[threadIdx.x] = 0;
}

// ---------------------------------------------------------------------------
// Gate: sgate (signed renormalized weights, 0 for dropped) + compacted
// per-expert row lists (order from atomicAdd — irrelevant, rows independent).
// ---------------------------------------------------------------------------
__global__ void gate_kernel(const float* __restrict__ x,
                            const float* __restrict__ gw,
                            const float* __restrict__ gb,
                            float* __restrict__ sgate,
                            int* __restrict__ cnt,
                            int* __restrict__ idx) {
  const int row = blockIdx.x * 4 + (threadIdx.x >> 6);
  const int l = threadIdx.x & 63;
  const float* xr = x + (size_t)row * DIN;
  float acc[8] = {0.f,0.f,0.f,0.f,0.f,0.f,0.f,0.f};
#pragma unroll
  for (int j = 0; j < 16; ++j) {
    const int k = l + 64 * j;
    const float xv = xr[k];
    const float4 g0 = *(const float4*)(gw + (size_t)k * 8);
    const float4 g1 = *(const float4*)(gw + (size_t)k * 8 + 4);
    acc[0] += xv * g0.x; acc[1] += xv * g0.y; acc[2] += xv * g0.z; acc[3] += xv * g0.w;
    acc[4] += xv * g1.x; acc[5] += xv * g1.y; acc[6] += xv * g1.z; acc[7] += xv * g1.w;
  }
#pragma unroll
  for (int off = 32; off > 0; off >>= 1) {
#pragma unroll
    for (int e = 0; e < 8; ++e) acc[e] += __shfl_xor(acc[e], off, 64);
  }
  if (l == 0) {
    const float invT = 0.36787944117144233f;
    float p[8]; float mx = -1e30f;
#pragma unroll
    for (int e = 0; e < 8; ++e) { p[e] = (acc[e] + gb[e]) * invT; mx = fmaxf(mx, p[e]); }
    float S = 0.f;
#pragma unroll
    for (int e = 0; e < 8; ++e) { p[e] = expf(p[e] - mx); S += p[e]; }
    const float inv = 1.0f / S;
#pragma unroll
    for (int e = 0; e < 8; ++e) p[e] *= inv;
    bool keep[8] = {true,true,true,true,true,true,true,true};
    for (int t = 0; t < 3; ++t) {
      float pmin = 1e30f; int mi = -1;
      for (int e = 0; e < 8; ++e)
        if (keep[e] && (p[e] < pmin || (p[e] == pmin && e > mi))) { pmin = p[e]; mi = e; }
      keep[mi] = false;
    }
    float wsum = 0.f;
#pragma unroll
    for (int e = 0; e < 8; ++e) if (keep[e]) wsum += p[e];
    const float rinv = 1.0f / (wsum + 1e-8f);
#pragma unroll
    for (int e = 0; e < 8; ++e) {
      const float wv = keep[e] ? p[e] * rinv : 0.0f;
      sgate[(size_t)row * 8 + e] = (e < 4) ? wv : -wv;
    }
    for (int e = 0; e < 8; ++e)
      if (keep[e]) {
        const int pos = atomicAdd(&cnt[e], 1);
        idx[e * NROWS + pos] = row;
      }
  }
}

__global__ void cvt_x_kernel(const float* __restrict__ x, f16* __restrict__ xh) {
  const size_t i = ((size_t)blockIdx.x * blockDim.x + threadIdx.x) * 4;
  const float4 v = *(const float4*)(x + i);
  f16x4 o = { (f16)v.x, (f16)v.y, (f16)v.z, (f16)v.w };
  *(f16x4*)(xh + i) = o;
}

// in f32 [E][R][C] -> out fp16 [E][C][R]
__global__ void transpose_cvt(const float* __restrict__ in, f16* __restrict__ out,
                              int R, int C) {
  __shared__ float tile[32][33];
  const int e = blockIdx.z;
  const float* ine = in + (size_t)e * R * C;
  f16* oute = out + (size_t)e * R * C;
  const int c0 = blockIdx.x * 32, r0 = blockIdx.y * 32;
  const int tx = threadIdx.x, ty = threadIdx.y;
#pragma unroll
  for (int i = 0; i < 4; ++i)
    tile[ty + i * 8][tx] = ine[(size_t)(r0 + ty + i * 8) * C + c0 + tx];
  __syncthreads();
#pragma unroll
  for (int i = 0; i < 4; ++i)
    oute[(size_t)(c0 + ty + i * 8) * R + r0 + tx] = (f16)tile[tx][ty + i * 8];
}

#define MFMAOP(a_, b_, c_) __builtin_amdgcn_mfma_f32_16x16x32_f16(a_, b_, c_, 0, 0, 0)

// ---------------------------------------------------------------------------
// gemm8p: 256x256 BK=64, 4 phases/tile, 4 half-tile LDS slots per operand
//   (R4-proven schedule/ledger/swizzle, unchanged). 8 waves, wave 128x64.
//   NEW (R10): row compaction. Me = cnt[expert]; Mpad = roundup256(Me);
//   blocks with m0 >= Mpad exit before any barrier/LDS.
// EPI=1: A-rows gathered through idx_e (4 indirect row bases per thread,
//   computed once; slots >= Me clamp to row 0 — garbage flows to hh pad
//   rows which GEMM2 skips). Epilogue: hh[slot][col] = f16(sg*relu(acc+b)),
//   compact, sg looked up via idx.
// EPI=2: A = compact hh; split-K=2 (kh = XCD>>2): Aeff/Beff column-half
//   offset +kh*2048; P = kh ? P1 : out, ALWAYS RMW (buffers zero-init).
//   Epilogue: per-wave LDS bounce -> float4 scatter-RMW via idx_e
//   (slots >= Me skipped).
// ---------------------------------------------------------------------------
template <int EPI>
__global__ __launch_bounds__(512, 2) void gemm8p(
    const f16* __restrict__ A, int lda,
    const f16* __restrict__ B, int ldb, int nt,
    const int* __restrict__ idx_e, const int* __restrict__ cntp,
    const float* __restrict__ bias,
    f16* __restrict__ outH, int ldc,
    float* outP0, float* outP1,
    const float* __restrict__ sgate, int expert, int gx) {
  __shared__ alignas(16) f16 lA[4 * 8192];   // 4 half-tile slots x 16KB
  __shared__ alignas(16) f16 lB[4 * 8192];
  const int tid = threadIdx.x;
  const int l = tid & 63, w = tid >> 6;
  const int wr = w >> 2, wc = w & 3;

  // T1 XCD swizzle (grid % 8 == 0); lg/cpx == XCD id
  const int nwg = gridDim.x, cpx = nwg >> 3;
  const int lg = ((int)blockIdx.x & 7) * cpx + ((int)blockIdx.x >> 3);

  const int Me = cntp[expert];
  const int Mpad = (Me + 255) & ~255;

  int m0, n0;
  const f16* Aeff = A;
  const f16* Beff = B;
  float* P = nullptr;
  if constexpr (EPI == 1) {
    // XCD n-partitioned: nper = gx/8 n-tiles per XCD -> 1MB B-set in L2.
    const int xcd = lg / cpx;
    const int cc = lg - xcd * cpx;
    const int nper = gx >> 3;
    m0 = (cc / nper) * 256;
    n0 = (xcd * nper + (cc % nper)) * 256;
  } else {
    const int xx = lg >> 5, cc = lg & 31;   // xx = XCD id, grid == 256
    const int kh = xx >> 2;                 // XCD 0-3 -> K-half 0; 4-7 -> 1
    n0 = (xx & 3) * 256;                    // one n-tile per XCD
    m0 = cc * 256;
    Aeff = A + kh * 2048;                   // column half of compact hh
    Beff = B + kh * 2048;                   // column half of w2t_e
    P = kh ? outP1 : outP0;
  }
  if (m0 >= Mpad) return;   // block-uniform early exit (before any barrier)

  // staging: thread -> (row srow in [0,64), chunk tid&7); chunk pre-swizzled
  const int srow = tid >> 3;
  const int sxc = (tid & 7) ^ (srow & 7);
  // A row bases: 4 rows per thread (h in {0,1} x {first,second} 64-row set)
  const f16 *pA00, *pA01, *pA10, *pA11;
  if constexpr (EPI == 1) {
    const int r00 = m0 + srow,       r01 = m0 + 64 + srow;
    const int r10 = m0 + 128 + srow, r11 = m0 + 192 + srow;
    pA00 = A + (size_t)((r00 < Me) ? idx_e[r00] : 0) * lda + sxc * 8;
    pA01 = A + (size_t)((r01 < Me) ? idx_e[r01] : 0) * lda + sxc * 8;
    pA10 = A + (size_t)((r10 < Me) ? idx_e[r10] : 0) * lda + sxc * 8;
    pA11 = A + (size_t)((r11 < Me) ? idx_e[r11] : 0) * lda + sxc * 8;
  } else {
    pA00 = Aeff + (size_t)(m0 + srow) * lda + sxc * 8;
    pA01 = pA00 + (size_t)64 * lda;
    pA10 = pA00 + (size_t)128 * lda;
    pA11 = pA00 + (size_t)192 * lda;
  }
  const f16* pB = Beff + (size_t)(n0 + srow) * ldb + sxc * 8;
  f16* const dA = lA + w * 512;   // wave-uniform LDS base (+ lane*16B by HW)
  f16* const dB = lB + w * 512;

#define STG_A(slot, h, tk) do { \
    const size_t kb = (size_t)(tk) * 64; \
    gload_lds16(((h) ? pA10 : pA00) + kb, dA + (slot) * 8192); \
    gload_lds16(((h) ? pA11 : pA01) + kb, dA + (slot) * 8192 + 4096); \
  } while (0)
#define STG_B(slot, h, tk) do { \
    const f16* s_ = pB + (size_t)(h) * 128 * ldb + (size_t)(tk) * 64; \
    gload_lds16(s_,            dB + (slot) * 8192); \
    gload_lds16(s_ + 64 * ldb, dB + (slot) * 8192 + 4096); \
  } while (0)

  // ds_read fragment offsets (bytes), same xor involution as the source
  const int cg = l >> 4, xr = l & 7;
  const int ok0 = ((cg ^ xr) << 4);
  const int ok1 = (((4 + cg) ^ xr) << 4);
  const char* const baA = (const char*)lA + (l & 15) * 128;
  const char* const baB = (const char*)lB + (wc & 1) * 8192 + (l & 15) * 128;

#define RDA(CA, f, o) (*(const f16x8*)(baA + ((CA) + wr) * 16384 + (f) * 2048 + (o)))
#define RDB(CB, g, o) (*(const f16x8*)(baB + ((CB) + (wc >> 1)) * 16384 + (g) * 2048 + (o)))

#define SB0() __builtin_amdgcn_sched_barrier(0)
#define SYNC() do { SB0(); __builtin_amdgcn_s_barrier(); SB0(); } while (0)
#define ENDPH() do { __builtin_amdgcn_s_setprio(0); SB0(); \
    __builtin_amdgcn_s_barrier(); SB0(); } while (0)
#define VM6() do { SB0(); asm volatile("s_waitcnt vmcnt(6)"); SB0(); } while (0)
#define VM0() do { SB0(); asm volatile("s_waitcnt vmcnt(0)"); SB0(); } while (0)
#define MM(f, g, ar, br) acc[f][g] = MFMAOP(ar, br, acc[f][g])

  f32x4 acc[8][4] = {};
  f16x8 fa0, fa1, fa2, fa3;          // A frags ks0 (phase-local)
  f16x8 ga0, ga1, ga2, ga3;          // A frags ks1
  f16x8 b00, b10, b20, b30;          // B g0-3 ks0 (live p0->p2)
  f16x8 b01, b11, b21, b31;          // B g0-3 ks1 (live p1->p3)

#define TILEBODY(T, CA, CB, SB1, SB0n, SA0n, SA1n) do { \
    /* phase 0: ks0 reads (8), MFMA f0-3 x g0-3 ks0 */ \
    fa0 = RDA(CA, 0, ok0); fa1 = RDA(CA, 1, ok0); \
    fa2 = RDA(CA, 2, ok0); fa3 = RDA(CA, 3, ok0); \
    b00 = RDB(CB, 0, ok0); b10 = RDB(CB, 1, ok0); \
    b20 = RDB(CB, 2, ok0); b30 = RDB(CB, 3, ok0); \
    if ((T) + 1 < nt) STG_B(SB1, 1, (T) + 1); \
    SYNC(); \
    __builtin_amdgcn_s_setprio(1); \
    MM(0,0,fa0,b00); MM(0,1,fa0,b10); MM(0,2,fa0,b20); MM(0,3,fa0,b30); \
    MM(1,0,fa1,b00); MM(1,1,fa1,b10); MM(1,2,fa1,b20); MM(1,3,fa1,b30); \
    MM(2,0,fa2,b00); MM(2,1,fa2,b10); MM(2,2,fa2,b20); MM(2,3,fa2,b30); \
    MM(3,0,fa3,b00); MM(3,1,fa3,b10); MM(3,2,fa3,b20); MM(3,3,fa3,b30); \
    ENDPH(); \
    /* phase 1: ks1 reads (8), MFMA f0-3 x g0-3 ks1 */ \
    ga0 = RDA(CA, 0, ok1); ga1 = RDA(CA, 1, ok1); \
    ga2 = RDA(CA, 2, ok1); ga3 = RDA(CA, 3, ok1); \
    b01 = RDB(CB, 0, ok1); b11 = RDB(CB, 1, ok1); \
    b21 = RDB(CB, 2, ok1); b31 = RDB(CB, 3, ok1); \
    SYNC(); \
    __builtin_amdgcn_s_setprio(1); \
    MM(0,0,ga0,b01); MM(0,1,ga0,b11); MM(0,2,ga0,b21); MM(0,3,ga0,b31); \
    MM(1,0,ga1,b01); MM(1,1,ga1,b11); MM(1,2,ga1,b21); MM(1,3,ga1,b31); \
    MM(2,0,ga2,b01); MM(2,1,ga2,b11); MM(2,2,ga2,b21); MM(2,3,ga2,b31); \
    MM(3,0,ga3,b01); MM(3,1,ga3,b11); MM(3,2,ga3,b21); MM(3,3,ga3,b31); \
    ENDPH(); \
    /* phase 2: A f4-7 ks0+ks1 reads (8), MFMA f4-7 x g0-3 ks0 */ \
    fa0 = RDA(CA, 4, ok0); fa1 = RDA(CA, 5, ok0); \
    fa2 = RDA(CA, 6, ok0); fa3 = RDA(CA, 7, ok0); \
    ga0 = RDA(CA, 4, ok1); ga1 = RDA(CA, 5, ok1); \
    ga2 = RDA(CA, 6, ok1); ga3 = RDA(CA, 7, ok1); \
    if ((T) + 2 < nt) STG_B(SB0n, 0, (T) + 2); \
    SYNC(); \
    __builtin_amdgcn_s_setprio(1); \
    MM(4,0,fa0,b00); MM(4,1,fa0,b10); MM(4,2,fa0,b20); MM(4,3,fa0,b30); \
    MM(5,0,fa1,b00); MM(5,1,fa1,b10); MM(5,2,fa1,b20); MM(5,3,fa1,b30); \
    MM(6,0,fa2,b00); MM(6,1,fa2,b10); MM(6,2,fa2,b20); MM(6,3,fa2,b30); \
    MM(7,0,fa3,b00); MM(7,1,fa3,b10); MM(7,2,fa3,b20); MM(7,3,fa3,b30); \
    ENDPH(); \
    /* phase 3: stage A(T+2), counted vmcnt; MFMA f4-7 x g0-3 ks1 */ \
    if ((T) + 2 < nt) { STG_A(SA0n, 0, (T) + 2); STG_A(SA1n, 1, (T) + 2); \
                        VM6(); } \
    else { VM0(); } \
    SYNC(); \
    __builtin_amdgcn_s_setprio(1); \
    MM(4,0,ga0,b01); MM(4,1,ga0,b11); MM(4,2,ga0,b21); MM(4,3,ga0,b31); \
    MM(5,0,ga1,b01); MM(5,1,ga1,b11); MM(5,2,ga1,b21); MM(5,3,ga1,b31); \
    MM(6,0,ga2,b01); MM(6,1,ga2,b11); MM(6,2,ga2,b21); MM(6,3,ga2,b31); \
    MM(7,0,ga3,b01); MM(7,1,ga3,b11); MM(7,2,ga3,b21); MM(7,3,ga3,b31); \
    ENDPH(); \
  } while (0)

  // prologue: tile0 (A0,B0,A1,B1) + tile1 (A0,B0,A1); 14 loads, drain to 6
  STG_A(0, 0, 0); STG_B(0, 0, 0); STG_A(1, 1, 0); STG_B(1, 1, 0);
  STG_A(2, 0, 1); STG_B(2, 0, 1); STG_A(3, 1, 1);
  SB0();
  asm volatile("s_waitcnt vmcnt(6)");
  SB0();
  __builtin_amdgcn_s_barrier();
  SB0();

  for (int t = 0; t < nt; t += 2) {
    TILEBODY(t,     0, 0, 3, 0, 0, 1);
    TILEBODY(t + 1, 2, 2, 1, 2, 2, 3);
  }
  SB0();
  asm volatile("s_waitcnt vmcnt(0)");
  SB0();

  // epilogue
  if constexpr (EPI == 1) {
#pragma unroll
    for (int mi = 0; mi < 8; ++mi)
#pragma unroll
      for (int r = 0; r < 4; ++r) {
        const int slot = m0 + wr * 128 + mi * 16 + (l >> 4) * 4 + r;
        const int grow = (slot < Me) ? idx_e[slot] : 0;
        const float sg = sgate[(size_t)grow * 8 + expert];
#pragma unroll
        for (int ni = 0; ni < 4; ++ni) {
          const int col = n0 + wc * 64 + ni * 16 + (l & 15);
          const float v = acc[mi][ni][r] + bias[col];
          outH[(size_t)slot * ldc + col] = (f16)(fmaxf(v, 0.0f) * sg);
        }
      }
  } else {
    // float4 LDS-bounce scatter-RMW epilogue; LDS free after final barrier.
    float* const scr = (w < 4) ? (float*)lA + w * 4096
                               : (float*)lB + (w - 4) * 4096;
    const int hl = l >> 4, ll = l & 15;
#pragma unroll
    for (int p = 0; p < 2; ++p) {
#pragma unroll
      for (int mi4 = 0; mi4 < 4; ++mi4)
#pragma unroll
        for (int r = 0; r < 4; ++r) {
          const int rowl = mi4 * 16 + hl * 4 + r;
#pragma unroll
          for (int ni = 0; ni < 4; ++ni)
            scr[rowl * 64 + ni * 16 + ll] = acc[p * 4 + mi4][ni][r];
        }
#pragma unroll
      for (int i = 0; i < 16; ++i) {
        const int rowl = hl + i * 4;
        const int slot = m0 + wr * 128 + p * 64 + rowl;
        if (slot < Me) {
          f32x4 v = *(const f32x4*)(scr + rowl * 64 + ll * 4);
          const int grow = idx_e[slot];
          const int col = n0 + wc * 64 + ll * 4;
          f32x4* gp = (f32x4*)(P + (size_t)grow * 1024 + col);
          const f32x4 g = *gp;
          v[0] += g[0]; v[1] += g[1]; v[2] += g[2]; v[3] += g[3];
          *gp = v;
        }
      }
    }
  }
#undef STG_A
#undef STG_B
#undef RDA
#undef RDB
#undef SB0
#undef SYNC
#undef ENDPH
#undef VM6
#undef VM0
#undef MM
#undef TILEBODY
}

// out = p0 + p1 + sum_e sg[n,e]*b2[e,:]   (float4-vectorized)
// NOTE: p0 aliases out -> no __restrict__ on p0/out.
__global__ void finalize_out(const float* p0,
                             const float* __restrict__ p1,
                             const float* __restrict__ sgate,
                             const float* __restrict__ b2,
                             float* out) {
  const int i = blockIdx.x * 256 + threadIdx.x;   // float4 index, 2M total
  const int n = i >> 8, c4 = i & 255;
  const float4 u = ((const float4*)p0)[i];
  const float4 v = ((const float4*)p1)[i];
  float4 a = make_float4(u.x + v.x, u.y + v.y, u.z + v.z, u.w + v.w);
  const float* sg = sgate + (size_t)n * 8;
#pragma unroll
  for (int e = 0; e < 8; ++e) {
    const float s = sg[e];
    const float4 bv = ((const float4*)(b2 + (size_t)e * 1024))[c4];
    a.x += s * bv.x; a.y += s * bv.y; a.z += s * bv.z; a.w += s * bv.w;
  }
  ((float4*)out)[i] = a;
}

extern "C" void kernel_launch(void* const* d_in, const int* in_sizes, int n_in,
                              void* d_out, int out_size, void* d_ws, size_t ws_size,
                              hipStream_t stream) {
  const float* x  = (const float*)d_in[0];
  const float* gw = (const float*)d_in[1];
  const float* gb = (const float*)d_in[2];
  const float* w1 = (const float*)d_in[3];
  const float* b1 = (const float*)d_in[4];
  const float* w2 = (const float*)d_in[5];
  const float* b2 = (const float*)d_in[6];
  float* out = (float*)d_out;

  char* ws = (char*)d_ws;
  float* sgate = (float*)(ws + OFF_SGATE);
  int*   cnt   = (int*)(ws + OFF_CNT);
  int*   idx   = (int*)(ws + OFF_IDX);
  f16* xh  = (f16*)(ws + OFF_XH);
  f16* w1t = (f16*)(ws + OFF_W1T);
  f16* w2t = (f16*)(ws + OFF_W2T);
  float* p1 = (float*)(ws + OFF_P1);
  f16* hh  = (f16*)(ws + OFF_HH);

  zero_init<<<(NROWS * DOUT) / (256 * 4), 256, 0, stream>>>(out, p1, cnt);
  gate_kernel<<<NROWS / 4, 256, 0, stream>>>(x, gw, gb, sgate, cnt, idx);
  cvt_x_kernel<<<(NROWS * DIN) / (256 * 4), 256, 0, stream>>>(x, xh);
  transpose_cvt<<<dim3(DHID / 32, DIN / 32, NEXP), dim3(32, 8), 0, stream>>>(w1, w1t, DIN, DHID);
  transpose_cvt<<<dim3(DOUT / 32, DHID / 32, NEXP), dim3(32, 8), 0, stream>>>(w2, w2t, DHID, DOUT);

  for (int e = 0; e < NEXP; ++e) {
    // GEMM1: compact rows of xh (gathered) x w1t_e -> hh compact
    gemm8p<1><<<512, 512, 0, stream>>>(
        xh, DIN, w1t + (size_t)e * DHID * DIN, DIN, DIN / 64,
        idx + (size_t)e * NROWS, cnt,
        b1 + (size_t)e * DHID, hh, DHID,
        nullptr, nullptr, sgate, e, DHID / 256);
    // GEMM2: compact hh x w2t_e, split-K=2 -> scatter-RMW into out / P1
    gemm8p<2><<<256, 512, 0, stream>>>(
        hh, DHID, w2t + (size_t)e * DOUT * DHID, DHID, 2048 / 64,
        idx + (size_t)e * NROWS, cnt,
        nullptr, nullptr, 0,
        out, p1, sgate, e, DOUT / 256);
  }
  finalize_out<<<(NROWS * DOUT) / (256 * 4), 256, 0, stream>>>(
      out, p1, sgate, b2, out);
}

// Round 8
// 1576.576 us; speedup vs baseline: 1.2946x; 1.2946x over previous
//
#include <hip/hip_runtime.h>
#include <hip/hip_bf16.h>
#include <cmath>

// ---------------------------------------------------------------------------
// MoE "pure field": gate(softmax@T=e, top-5/8, renorm, sign) + dense 2-layer
// FFN over all experts, accumulated with signed gate weights.
//   N=8192, D_IN=1024, D_HID=4096, D_OUT=1024, E=8, k=5
// Round 11: fix R10's gate atomic-contention disaster (40960 same-line
//   device atomics = 474us serial). Gate reverts to proven form (sgate
//   only); NEW compact_kernel does ORDERED per-expert stream compaction
//   (ballot/popc prefix, zero global atomics, ~10us) -> idx sorted
//   ascending, which also restores gather/scatter DRAM locality in both
//   GEMMs. GEMM schedule/ledger/swizzle = R4-proven, unchanged from R10.
// ---------------------------------------------------------------------------

typedef _Float16 f16;
typedef _Float16 f16x8 __attribute__((ext_vector_type(8)));
typedef _Float16 f16x4 __attribute__((ext_vector_type(4)));
typedef float f32x4 __attribute__((ext_vector_type(4)));

#define NROWS 8192
#define DIN   1024
#define DHID  4096
#define DOUT  1024
#define NEXP  8

// workspace layout (bytes)
#define OFF_SGATE 0u            // sgate: 8192x8 f32 = 256KB
#define OFF_CNT   262144u       // cnt: 8 ints (+pad 4KB)
#define OFF_IDX   266240u       // idx: 8 x 8192 ints = 256KB
#define OFF_XH    528384u       // xh: 8192x1024 f16 = 16MB
#define OFF_W1T   17305600u     // w1t: 8x4096x1024 f16 = 64MB
#define OFF_W2T   84414464u     // w2t: 8x1024x4096 f16 = 64MB
#define OFF_P1    151523328u    // P1 partial f32 = 32MB
#define OFF_HH    185077760u    // hh compact: 8192x4096 f16 = 64MB

__device__ __forceinline__ void gload_lds16(const void* gsrc, void* ldsdst) {
  __builtin_amdgcn_global_load_lds(
      (const __attribute__((address_space(1))) unsigned int*)gsrc,
      (__attribute__((address_space(3))) unsigned int*)ldsdst, 16, 0, 0);
}

// zero out (8M f32) + P1 (8M f32).
__global__ void zero_init(float* __restrict__ out, float* __restrict__ p1) {
  const size_t i = (size_t)blockIdx.x * 256 + threadIdx.x;
  const float4 z = make_float4(0.f, 0.f, 0.f, 0.f);
  ((float4*)out)[i] = z;
  ((float4*)p1)[i] = z;
}

// ---------------------------------------------------------------------------
// Gate (proven form): sgate = signed renormalized weights, 0 for dropped.
// ---------------------------------------------------------------------------
__global__ void gate_kernel(const float* __restrict__ x,
                            const float* __restrict__ gw,
                            const float* __restrict__ gb,
                            float* __restrict__ sgate) {
  const int row = blockIdx.x * 4 + (threadIdx.x >> 6);
  const int l = threadIdx.x & 63;
  const float* xr = x + (size_t)row * DIN;
  float acc[8] = {0.f,0.f,0.f,0.f,0.f,0.f,0.f,0.f};
#pragma unroll
  for (int j = 0; j < 16; ++j) {
    const int k = l + 64 * j;
    const float xv = xr[k];
    const float4 g0 = *(const float4*)(gw + (size_t)k * 8);
    const float4 g1 = *(const float4*)(gw + (size_t)k * 8 + 4);
    acc[0] += xv * g0.x; acc[1] += xv * g0.y; acc[2] += xv * g0.z; acc[3] += xv * g0.w;
    acc[4] += xv * g1.x; acc[5] += xv * g1.y; acc[6] += xv * g1.z; acc[7] += xv * g1.w;
  }
#pragma unroll
  for (int off = 32; off > 0; off >>= 1) {
#pragma unroll
    for (int e = 0; e < 8; ++e) acc[e] += __shfl_xor(acc[e], off, 64);
  }
  if (l == 0) {
    const float invT = 0.36787944117144233f;
    float p[8]; float mx = -1e30f;
#pragma unroll
    for (int e = 0; e < 8; ++e) { p[e] = (acc[e] + gb[e]) * invT; mx = fmaxf(mx, p[e]); }
    float S = 0.f;
#pragma unroll
    for (int e = 0; e < 8; ++e) { p[e] = expf(p[e] - mx); S += p[e]; }
    const float inv = 1.0f / S;
#pragma unroll
    for (int e = 0; e < 8; ++e) p[e] *= inv;
    bool keep[8] = {true,true,true,true,true,true,true,true};
    for (int t = 0; t < 3; ++t) {
      float pmin = 1e30f; int mi = -1;
      for (int e = 0; e < 8; ++e)
        if (keep[e] && (p[e] < pmin || (p[e] == pmin && e > mi))) { pmin = p[e]; mi = e; }
      keep[mi] = false;
    }
    float wsum = 0.f;
#pragma unroll
    for (int e = 0; e < 8; ++e) if (keep[e]) wsum += p[e];
    const float rinv = 1.0f / (wsum + 1e-8f);
#pragma unroll
    for (int e = 0; e < 8; ++e) {
      const float wv = keep[e] ? p[e] * rinv : 0.0f;
      sgate[(size_t)row * 8 + e] = (e < 4) ? wv : -wv;
    }
  }
}

// ---------------------------------------------------------------------------
// Ordered per-expert compaction: one block per expert, 1024 threads.
// idx[e][pos] = ascending rows with sgate[row][e] != 0; cnt[e] = count.
// Zero global atomics (the R10 version's 40960 same-line device atomics
// serialized to 474us). Ballot/popc wave prefix + LDS cross-wave scan.
// ---------------------------------------------------------------------------
__global__ void compact_kernel(const float* __restrict__ sgate,
                               int* __restrict__ cnt,
                               int* __restrict__ idx) {
  const int e = blockIdx.x;
  const int tid = threadIdx.x;
  const int wv = tid >> 6, ln = tid & 63;
  __shared__ int wsum[16];
  __shared__ int base;
  if (tid == 0) base = 0;
  __syncthreads();
  int* idx_e = idx + e * NROWS;
  for (int r0 = 0; r0 < NROWS; r0 += 1024) {
    const int row = r0 + tid;
    const bool keep = sgate[(size_t)row * 8 + e] != 0.0f;
    const unsigned long long m = __ballot(keep);
    if (ln == 0) wsum[wv] = __popcll(m);
    __syncthreads();
    int wbase = base;
    for (int i = 0; i < wv; ++i) wbase += wsum[i];
    if (keep)
      idx_e[wbase + __popcll(m & ((1ull << ln) - 1ull))] = row;
    __syncthreads();
    if (tid == 0) {
      int tot = 0;
      for (int i = 0; i < 16; ++i) tot += wsum[i];
      base += tot;
    }
    __syncthreads();
  }
  if (tid == 0) cnt[e] = base;
}

__global__ void cvt_x_kernel(const float* __restrict__ x, f16* __restrict__ xh) {
  const size_t i = ((size_t)blockIdx.x * blockDim.x + threadIdx.x) * 4;
  const float4 v = *(const float4*)(x + i);
  f16x4 o = { (f16)v.x, (f16)v.y, (f16)v.z, (f16)v.w };
  *(f16x4*)(xh + i) = o;
}

// in f32 [E][R][C] -> out fp16 [E][C][R]
__global__ void transpose_cvt(const float* __restrict__ in, f16* __restrict__ out,
                              int R, int C) {
  __shared__ float tile[32][33];
  const int e = blockIdx.z;
  const float* ine = in + (size_t)e * R * C;
  f16* oute = out + (size_t)e * R * C;
  const int c0 = blockIdx.x * 32, r0 = blockIdx.y * 32;
  const int tx = threadIdx.x, ty = threadIdx.y;
#pragma unroll
  for (int i = 0; i < 4; ++i)
    tile[ty + i * 8][tx] = ine[(size_t)(r0 + ty + i * 8) * C + c0 + tx];
  __syncthreads();
#pragma unroll
  for (int i = 0; i < 4; ++i)
    oute[(size_t)(c0 + ty + i * 8) * R + r0 + tx] = (f16)tile[tx][ty + i * 8];
}

#define MFMAOP(a_, b_, c_) __builtin_amdgcn_mfma_f32_16x16x32_f16(a_, b_, c_, 0, 0, 0)

// ---------------------------------------------------------------------------
// gemm8p: 256x256 BK=64, 4 phases/tile, 4 half-tile LDS slots per operand
//   (R4-proven schedule/ledger/swizzle). 8 waves, wave 128x64.
//   Row compaction: Me = cnt[expert]; Mpad = roundup256(Me); blocks with
//   m0 >= Mpad exit before any barrier/LDS. idx is SORTED ascending (R11).
// EPI=1: A-rows gathered through idx_e (4 indirect row bases per thread);
//   epilogue: hh[slot][col] = f16(sg*relu(acc+b)), compact.
// EPI=2: A = compact hh; split-K=2 (kh = XCD>>2); P = kh ? P1 : out, RMW
//   (buffers zero-init). Epilogue: LDS bounce -> float4 scatter-RMW via
//   idx_e (slots >= Me skipped).
// ---------------------------------------------------------------------------
template <int EPI>
__global__ __launch_bounds__(512, 2) void gemm8p(
    const f16* __restrict__ A, int lda,
    const f16* __restrict__ B, int ldb, int nt,
    const int* __restrict__ idx_e, const int* __restrict__ cntp,
    const float* __restrict__ bias,
    f16* __restrict__ outH, int ldc,
    float* outP0, float* outP1,
    const float* __restrict__ sgate, int expert, int gx) {
  __shared__ alignas(16) f16 lA[4 * 8192];   // 4 half-tile slots x 16KB
  __shared__ alignas(16) f16 lB[4 * 8192];
  const int tid = threadIdx.x;
  const int l = tid & 63, w = tid >> 6;
  const int wr = w >> 2, wc = w & 3;

  // T1 XCD swizzle (grid % 8 == 0); lg/cpx == XCD id
  const int nwg = gridDim.x, cpx = nwg >> 3;
  const int lg = ((int)blockIdx.x & 7) * cpx + ((int)blockIdx.x >> 3);

  const int Me = cntp[expert];
  const int Mpad = (Me + 255) & ~255;

  int m0, n0;
  const f16* Aeff = A;
  const f16* Beff = B;
  float* P = nullptr;
  if constexpr (EPI == 1) {
    // XCD n-partitioned: nper = gx/8 n-tiles per XCD -> 1MB B-set in L2.
    const int xcd = lg / cpx;
    const int cc = lg - xcd * cpx;
    const int nper = gx >> 3;
    m0 = (cc / nper) * 256;
    n0 = (xcd * nper + (cc % nper)) * 256;
  } else {
    const int xx = lg >> 5, cc = lg & 31;   // xx = XCD id, grid == 256
    const int kh = xx >> 2;                 // XCD 0-3 -> K-half 0; 4-7 -> 1
    n0 = (xx & 3) * 256;                    // one n-tile per XCD
    m0 = cc * 256;
    Aeff = A + kh * 2048;                   // column half of compact hh
    Beff = B + kh * 2048;                   // column half of w2t_e
    P = kh ? outP1 : outP0;
  }
  if (m0 >= Mpad) return;   // block-uniform early exit (before any barrier)

  // staging: thread -> (row srow in [0,64), chunk tid&7); chunk pre-swizzled
  const int srow = tid >> 3;
  const int sxc = (tid & 7) ^ (srow & 7);
  // A row bases: 4 rows per thread (h in {0,1} x {first,second} 64-row set)
  const f16 *pA00, *pA01, *pA10, *pA11;
  if constexpr (EPI == 1) {
    const int r00 = m0 + srow,       r01 = m0 + 64 + srow;
    const int r10 = m0 + 128 + srow, r11 = m0 + 192 + srow;
    pA00 = A + (size_t)((r00 < Me) ? idx_e[r00] : 0) * lda + sxc * 8;
    pA01 = A + (size_t)((r01 < Me) ? idx_e[r01] : 0) * lda + sxc * 8;
    pA10 = A + (size_t)((r10 < Me) ? idx_e[r10] : 0) * lda + sxc * 8;
    pA11 = A + (size_t)((r11 < Me) ? idx_e[r11] : 0) * lda + sxc * 8;
  } else {
    pA00 = Aeff + (size_t)(m0 + srow) * lda + sxc * 8;
    pA01 = pA00 + (size_t)64 * lda;
    pA10 = pA00 + (size_t)128 * lda;
    pA11 = pA00 + (size_t)192 * lda;
  }
  const f16* pB = Beff + (size_t)(n0 + srow) * ldb + sxc * 8;
  f16* const dA = lA + w * 512;   // wave-uniform LDS base (+ lane*16B by HW)
  f16* const dB = lB + w * 512;

#define STG_A(slot, h, tk) do { \
    const size_t kb = (size_t)(tk) * 64; \
    gload_lds16(((h) ? pA10 : pA00) + kb, dA + (slot) * 8192); \
    gload_lds16(((h) ? pA11 : pA01) + kb, dA + (slot) * 8192 + 4096); \
  } while (0)
#define STG_B(slot, h, tk) do { \
    const f16* s_ = pB + (size_t)(h) * 128 * ldb + (size_t)(tk) * 64; \
    gload_lds16(s_,            dB + (slot) * 8192); \
    gload_lds16(s_ + 64 * ldb, dB + (slot) * 8192 + 4096); \
  } while (0)

  // ds_read fragment offsets (bytes), same xor involution as the source
  const int cg = l >> 4, xr = l & 7;
  const int ok0 = ((cg ^ xr) << 4);
  const int ok1 = (((4 + cg) ^ xr) << 4);
  const char* const baA = (const char*)lA + (l & 15) * 128;
  const char* const baB = (const char*)lB + (wc & 1) * 8192 + (l & 15) * 128;

#define RDA(CA, f, o) (*(const f16x8*)(baA + ((CA) + wr) * 16384 + (f) * 2048 + (o)))
#define RDB(CB, g, o) (*(const f16x8*)(baB + ((CB) + (wc >> 1)) * 16384 + (g) * 2048 + (o)))

#define SB0() __builtin_amdgcn_sched_barrier(0)
#define SYNC() do { SB0(); __builtin_amdgcn_s_barrier(); SB0(); } while (0)
#define ENDPH() do { __builtin_amdgcn_s_setprio(0); SB0(); \
    __builtin_amdgcn_s_barrier(); SB0(); } while (0)
#define VM6() do { SB0(); asm volatile("s_waitcnt vmcnt(6)"); SB0(); } while (0)
#define VM0() do { SB0(); asm volatile("s_waitcnt vmcnt(0)"); SB0(); } while (0)
#define MM(f, g, ar, br) acc[f][g] = MFMAOP(ar, br, acc[f][g])

  f32x4 acc[8][4] = {};
  f16x8 fa0, fa1, fa2, fa3;          // A frags ks0 (phase-local)
  f16x8 ga0, ga1, ga2, ga3;          // A frags ks1
  f16x8 b00, b10, b20, b30;          // B g0-3 ks0 (live p0->p2)
  f16x8 b01, b11, b21, b31;          // B g0-3 ks1 (live p1->p3)

#define TILEBODY(T, CA, CB, SB1, SB0n, SA0n, SA1n) do { \
    /* phase 0: ks0 reads (8), MFMA f0-3 x g0-3 ks0 */ \
    fa0 = RDA(CA, 0, ok0); fa1 = RDA(CA, 1, ok0); \
    fa2 = RDA(CA, 2, ok0); fa3 = RDA(CA, 3, ok0); \
    b00 = RDB(CB, 0, ok0); b10 = RDB(CB, 1, ok0); \
    b20 = RDB(CB, 2, ok0); b30 = RDB(CB, 3, ok0); \
    if ((T) + 1 < nt) STG_B(SB1, 1, (T) + 1); \
    SYNC(); \
    __builtin_amdgcn_s_setprio(1); \
    MM(0,0,fa0,b00); MM(0,1,fa0,b10); MM(0,2,fa0,b20); MM(0,3,fa0,b30); \
    MM(1,0,fa1,b00); MM(1,1,fa1,b10); MM(1,2,fa1,b20); MM(1,3,fa1,b30); \
    MM(2,0,fa2,b00); MM(2,1,fa2,b10); MM(2,2,fa2,b20); MM(2,3,fa2,b30); \
    MM(3,0,fa3,b00); MM(3,1,fa3,b10); MM(3,2,fa3,b20); MM(3,3,fa3,b30); \
    ENDPH(); \
    /* phase 1: ks1 reads (8), MFMA f0-3 x g0-3 ks1 */ \
    ga0 = RDA(CA, 0, ok1); ga1 = RDA(CA, 1, ok1); \
    ga2 = RDA(CA, 2, ok1); ga3 = RDA(CA, 3, ok1); \
    b01 = RDB(CB, 0, ok1); b11 = RDB(CB, 1, ok1); \
    b21 = RDB(CB, 2, ok1); b31 = RDB(CB, 3, ok1); \
    SYNC(); \
    __builtin_amdgcn_s_setprio(1); \
    MM(0,0,ga0,b01); MM(0,1,ga0,b11); MM(0,2,ga0,b21); MM(0,3,ga0,b31); \
    MM(1,0,ga1,b01); MM(1,1,ga1,b11); MM(1,2,ga1,b21); MM(1,3,ga1,b31); \
    MM(2,0,ga2,b01); MM(2,1,ga2,b11); MM(2,2,ga2,b21); MM(2,3,ga2,b31); \
    MM(3,0,ga3,b01); MM(3,1,ga3,b11); MM(3,2,ga3,b21); MM(3,3,ga3,b31); \
    ENDPH(); \
    /* phase 2: A f4-7 ks0+ks1 reads (8), MFMA f4-7 x g0-3 ks0 */ \
    fa0 = RDA(CA, 4, ok0); fa1 = RDA(CA, 5, ok0); \
    fa2 = RDA(CA, 6, ok0); fa3 = RDA(CA, 7, ok0); \
    ga0 = RDA(CA, 4, ok1); ga1 = RDA(CA, 5, ok1); \
    ga2 = RDA(CA, 6, ok1); ga3 = RDA(CA, 7, ok1); \
    if ((T) + 2 < nt) STG_B(SB0n, 0, (T) + 2); \
    SYNC(); \
    __builtin_amdgcn_s_setprio(1); \
    MM(4,0,fa0,b00); MM(4,1,fa0,b10); MM(4,2,fa0,b20); MM(4,3,fa0,b30); \
    MM(5,0,fa1,b00); MM(5,1,fa1,b10); MM(5,2,fa1,b20); MM(5,3,fa1,b30); \
    MM(6,0,fa2,b00); MM(6,1,fa2,b10); MM(6,2,fa2,b20); MM(6,3,fa2,b30); \
    MM(7,0,fa3,b00); MM(7,1,fa3,b10); MM(7,2,fa3,b20); MM(7,3,fa3,b30); \
    ENDPH(); \
    /* phase 3: stage A(T+2), counted vmcnt; MFMA f4-7 x g0-3 ks1 */ \
    if ((T) + 2 < nt) { STG_A(SA0n, 0, (T) + 2); STG_A(SA1n, 1, (T) + 2); \
                        VM6(); } \
    else { VM0(); } \
    SYNC(); \
    __builtin_amdgcn_s_setprio(1); \
    MM(4,0,ga0,b01); MM(4,1,ga0,b11); MM(4,2,ga0,b21); MM(4,3,ga0,b31); \
    MM(5,0,ga1,b01); MM(5,1,ga1,b11); MM(5,2,ga1,b21); MM(5,3,ga1,b31); \
    MM(6,0,ga2,b01); MM(6,1,ga2,b11); MM(6,2,ga2,b21); MM(6,3,ga2,b31); \
    MM(7,0,ga3,b01); MM(7,1,ga3,b11); MM(7,2,ga3,b21); MM(7,3,ga3,b31); \
    ENDPH(); \
  } while (0)

  // prologue: tile0 (A0,B0,A1,B1) + tile1 (A0,B0,A1); 14 loads, drain to 6
  STG_A(0, 0, 0); STG_B(0, 0, 0); STG_A(1, 1, 0); STG_B(1, 1, 0);
  STG_A(2, 0, 1); STG_B(2, 0, 1); STG_A(3, 1, 1);
  SB0();
  asm volatile("s_waitcnt vmcnt(6)");
  SB0();
  __builtin_amdgcn_s_barrier();
  SB0();

  for (int t = 0; t < nt; t += 2) {
    TILEBODY(t,     0, 0, 3, 0, 0, 1);
    TILEBODY(t + 1, 2, 2, 1, 2, 2, 3);
  }
  SB0();
  asm volatile("s_waitcnt vmcnt(0)");
  SB0();

  // epilogue
  if constexpr (EPI == 1) {
#pragma unroll
    for (int mi = 0; mi < 8; ++mi)
#pragma unroll
      for (int r = 0; r < 4; ++r) {
        const int slot = m0 + wr * 128 + mi * 16 + (l >> 4) * 4 + r;
        const int grow = (slot < Me) ? idx_e[slot] : 0;
        const float sg = sgate[(size_t)grow * 8 + expert];
#pragma unroll
        for (int ni = 0; ni < 4; ++ni) {
          const int col = n0 + wc * 64 + ni * 16 + (l & 15);
          const float v = acc[mi][ni][r] + bias[col];
          outH[(size_t)slot * ldc + col] = (f16)(fmaxf(v, 0.0f) * sg);
        }
      }
  } else {
    // float4 LDS-bounce scatter-RMW epilogue; LDS free after final barrier.
    float* const scr = (w < 4) ? (float*)lA + w * 4096
                               : (float*)lB + (w - 4) * 4096;
    const int hl = l >> 4, ll = l & 15;
#pragma unroll
    for (int p = 0; p < 2; ++p) {
#pragma unroll
      for (int mi4 = 0; mi4 < 4; ++mi4)
#pragma unroll
        for (int r = 0; r < 4; ++r) {
          const int rowl = mi4 * 16 + hl * 4 + r;
#pragma unroll
          for (int ni = 0; ni < 4; ++ni)
            scr[rowl * 64 + ni * 16 + ll] = acc[p * 4 + mi4][ni][r];
        }
#pragma unroll
      for (int i = 0; i < 16; ++i) {
        const int rowl = hl + i * 4;
        const int slot = m0 + wr * 128 + p * 64 + rowl;
        if (slot < Me) {
          f32x4 v = *(const f32x4*)(scr + rowl * 64 + ll * 4);
          const int grow = idx_e[slot];
          const int col = n0 + wc * 64 + ll * 4;
          f32x4* gp = (f32x4*)(P + (size_t)grow * 1024 + col);
          const f32x4 g = *gp;
          v[0] += g[0]; v[1] += g[1]; v[2] += g[2]; v[3] += g[3];
          *gp = v;
        }
      }
    }
  }
#undef STG_A
#undef STG_B
#undef RDA
#undef RDB
#undef SB0
#undef SYNC
#undef ENDPH
#undef VM6
#undef VM0
#undef MM
#undef TILEBODY
}

// out = p0 + p1 + sum_e sg[n,e]*b2[e,:]   (float4-vectorized)
// NOTE: p0 aliases out -> no __restrict__ on p0/out.
__global__ void finalize_out(const float* p0,
                             const float* __restrict__ p1,
                             const float* __restrict__ sgate,
                             const float* __restrict__ b2,
                             float* out) {
  const int i = blockIdx.x * 256 + threadIdx.x;   // float4 index, 2M total
  const int n = i >> 8, c4 = i & 255;
  const float4 u = ((const float4*)p0)[i];
  const float4 v = ((const float4*)p1)[i];
  float4 a = make_float4(u.x + v.x, u.y + v.y, u.z + v.z, u.w + v.w);
  const float* sg = sgate + (size_t)n * 8;
#pragma unroll
  for (int e = 0; e < 8; ++e) {
    const float s = sg[e];
    const float4 bv = ((const float4*)(b2 + (size_t)e * 1024))[c4];
    a.x += s * bv.x; a.y += s * bv.y; a.z += s * bv.z; a.w += s * bv.w;
  }
  ((float4*)out)[i] = a;
}

extern "C" void kernel_launch(void* const* d_in, const int* in_sizes, int n_in,
                              void* d_out, int out_size, void* d_ws, size_t ws_size,
                              hipStream_t stream) {
  const float* x  = (const float*)d_in[0];
  const float* gw = (const float*)d_in[1];
  const float* gb = (const float*)d_in[2];
  const float* w1 = (const float*)d_in[3];
  const float* b1 = (const float*)d_in[4];
  const float* w2 = (const float*)d_in[5];
  const float* b2 = (const float*)d_in[6];
  float* out = (float*)d_out;

  char* ws = (char*)d_ws;
  float* sgate = (float*)(ws + OFF_SGATE);
  int*   cnt   = (int*)(ws + OFF_CNT);
  int*   idx   = (int*)(ws + OFF_IDX);
  f16* xh  = (f16*)(ws + OFF_XH);
  f16* w1t = (f16*)(ws + OFF_W1T);
  f16* w2t = (f16*)(ws + OFF_W2T);
  float* p1 = (float*)(ws + OFF_P1);
  f16* hh  = (f16*)(ws + OFF_HH);

  zero_init<<<(NROWS * DOUT) / (256 * 4), 256, 0, stream>>>(out, p1);
  gate_kernel<<<NROWS / 4, 256, 0, stream>>>(x, gw, gb, sgate);
  compact_kernel<<<NEXP, 1024, 0, stream>>>(sgate, cnt, idx);
  cvt_x_kernel<<<(NROWS * DIN) / (256 * 4), 256, 0, stream>>>(x, xh);
  transpose_cvt<<<dim3(DHID / 32, DIN / 32, NEXP), dim3(32, 8), 0, stream>>>(w1, w1t, DIN, DHID);
  transpose_cvt<<<dim3(DOUT / 32, DHID / 32, NEXP), dim3(32, 8), 0, stream>>>(w2, w2t, DHID, DOUT);

  for (int e = 0; e < NEXP; ++e) {
    // GEMM1: compact rows of xh (gathered) x w1t_e -> hh compact
    gemm8p<1><<<512, 512, 0, stream>>>(
        xh, DIN, w1t + (size_t)e * DHID * DIN, DIN, DIN / 64,
        idx + (size_t)e * NROWS, cnt,
        b1 + (size_t)e * DHID, hh, DHID,
        nullptr, nullptr, sgate, e, DHID / 256);
    // GEMM2: compact hh x w2t_e, split-K=2 -> scatter-RMW into out / P1
    gemm8p<2><<<256, 512, 0, stream>>>(
        hh, DHID, w2t + (size_t)e * DOUT * DHID, DHID, 2048 / 64,
        idx + (size_t)e * NROWS, cnt,
        nullptr, nullptr, 0,
        out, p1, sgate, e, DOUT / 256);
  }
  finalize_out<<<(NROWS * DOUT) / (256 * 4), 256, 0, stream>>>(
      out, p1, sgate, b2, out);
}

// Round 9
// 1422.678 us; speedup vs baseline: 1.4346x; 1.1082x over previous
//
#include <hip/hip_runtime.h>
#include <hip/hip_bf16.h>
#include <cmath>

// ---------------------------------------------------------------------------
// MoE "pure field": gate(softmax@T=e, top-5/8, renorm, sign) + dense 2-layer
// FFN over all experts, accumulated with signed gate weights.
//   N=8192, D_IN=1024, D_HID=4096, D_OUT=1024, E=8, k=5
// Round 12: dense revert + best-of-session recombination.
//   Sparse path (R10/R11) lost to gather/imbalance overhead -> dropped.
//   GEMM phase structure reverted to R1/R2's {12,4,8,0}-read TILEBODY
//   (B-frags persist all 4 phases) -- dispatch forensics show GEMM1 ran
//   ~44-68us in that era vs 74us after R4's {8,8,8,0} repartition.
//   Kept from R4: VM0 tail fix (ledger race), NE=2 expert grouping for
//   GEMM2 (XCD-partitioned split-K, LDS-bounce float4 RMW epilogue).
// ---------------------------------------------------------------------------

typedef _Float16 f16;
typedef _Float16 f16x8 __attribute__((ext_vector_type(8)));
typedef _Float16 f16x4 __attribute__((ext_vector_type(4)));
typedef float f32x4 __attribute__((ext_vector_type(4)));

#define NROWS 8192
#define DIN   1024
#define DHID  4096
#define DOUT  1024
#define NEXP  8

// workspace layout (bytes)
#define OFF_SGATE 0u
#define OFF_XH    262144u          // xh: 8192x1024 f16 = 16MB
#define OFF_W1T   17039360u        // w1t: 8x4096x1024 f16 = 64MB
#define OFF_W2T   84148224u        // w2t: 8x1024x4096 f16 = 64MB
#define OFF_P1    151257088u       // P1 partial f32 = 32MB
#define OFF_HH    184811520u       // hh group buffer: NE x 64MB
#define NEED_NE2  319029248ull

__device__ __forceinline__ void gload_lds16(const void* gsrc, void* ldsdst) {
  __builtin_amdgcn_global_load_lds(
      (const __attribute__((address_space(1))) unsigned int*)gsrc,
      (__attribute__((address_space(3))) unsigned int*)ldsdst, 16, 0, 0);
}

// ---------------------------------------------------------------------------
// Gate (proven form).
// ---------------------------------------------------------------------------
__global__ void gate_kernel(const float* __restrict__ x,
                            const float* __restrict__ gw,
                            const float* __restrict__ gb,
                            float* __restrict__ sgate) {
  const int row = blockIdx.x * 4 + (threadIdx.x >> 6);
  const int l = threadIdx.x & 63;
  const float* xr = x + (size_t)row * DIN;
  float acc[8] = {0.f,0.f,0.f,0.f,0.f,0.f,0.f,0.f};
#pragma unroll
  for (int j = 0; j < 16; ++j) {
    const int k = l + 64 * j;
    const float xv = xr[k];
    const float4 g0 = *(const float4*)(gw + (size_t)k * 8);
    const float4 g1 = *(const float4*)(gw + (size_t)k * 8 + 4);
    acc[0] += xv * g0.x; acc[1] += xv * g0.y; acc[2] += xv * g0.z; acc[3] += xv * g0.w;
    acc[4] += xv * g1.x; acc[5] += xv * g1.y; acc[6] += xv * g1.z; acc[7] += xv * g1.w;
  }
#pragma unroll
  for (int off = 32; off > 0; off >>= 1) {
#pragma unroll
    for (int e = 0; e < 8; ++e) acc[e] += __shfl_xor(acc[e], off, 64);
  }
  if (l == 0) {
    const float invT = 0.36787944117144233f;
    float p[8]; float mx = -1e30f;
#pragma unroll
    for (int e = 0; e < 8; ++e) { p[e] = (acc[e] + gb[e]) * invT; mx = fmaxf(mx, p[e]); }
    float S = 0.f;
#pragma unroll
    for (int e = 0; e < 8; ++e) { p[e] = expf(p[e] - mx); S += p[e]; }
    const float inv = 1.0f / S;
#pragma unroll
    for (int e = 0; e < 8; ++e) p[e] *= inv;
    bool keep[8] = {true,true,true,true,true,true,true,true};
    for (int t = 0; t < 3; ++t) {
      float pmin = 1e30f; int mi = -1;
      for (int e = 0; e < 8; ++e)
        if (keep[e] && (p[e] < pmin || (p[e] == pmin && e > mi))) { pmin = p[e]; mi = e; }
      keep[mi] = false;
    }
    float wsum = 0.f;
#pragma unroll
    for (int e = 0; e < 8; ++e) if (keep[e]) wsum += p[e];
    const float rinv = 1.0f / (wsum + 1e-8f);
#pragma unroll
    for (int e = 0; e < 8; ++e) {
      const float wv = keep[e] ? p[e] * rinv : 0.0f;
      sgate[(size_t)row * 8 + e] = (e < 4) ? wv : -wv;
    }
  }
}

__global__ void cvt_x_kernel(const float* __restrict__ x, f16* __restrict__ xh) {
  const size_t i = ((size_t)blockIdx.x * blockDim.x + threadIdx.x) * 4;
  const float4 v = *(const float4*)(x + i);
  f16x4 o = { (f16)v.x, (f16)v.y, (f16)v.z, (f16)v.w };
  *(f16x4*)(xh + i) = o;
}

// in f32 [E][R][C] -> out fp16 [E][C][R]
__global__ void transpose_cvt(const float* __restrict__ in, f16* __restrict__ out,
                              int R, int C) {
  __shared__ float tile[32][33];
  const int e = blockIdx.z;
  const float* ine = in + (size_t)e * R * C;
  f16* oute = out + (size_t)e * R * C;
  const int c0 = blockIdx.x * 32, r0 = blockIdx.y * 32;
  const int tx = threadIdx.x, ty = threadIdx.y;
#pragma unroll
  for (int i = 0; i < 4; ++i)
    tile[ty + i * 8][tx] = ine[(size_t)(r0 + ty + i * 8) * C + c0 + tx];
  __syncthreads();
#pragma unroll
  for (int i = 0; i < 4; ++i)
    oute[(size_t)(c0 + ty + i * 8) * R + r0 + tx] = (f16)tile[tx][ty + i * 8];
}

#define MFMAOP(a_, b_, c_) __builtin_amdgcn_mfma_f32_16x16x32_f16(a_, b_, c_, 0, 0, 0)

// ---------------------------------------------------------------------------
// gemm8p: 256x256 BK=64, 4 phases/tile, 4 half-tile LDS slots per operand.
//   R1/R2-era phase partition (best-measured for GEMM1):
//     p0: rd A f0-3 ks0+ks1 (8) + B g0-1 ks0+ks1 (4) | STG_B(T+1,h1) |
//         bar+lgkm0 | MFMA f0-3 x g0-1 x both ks (16)
//     p1: rd B g2-3 ks0+ks1 (4) | bar+lgkm0 | MFMA f0-3 x g2-3 (16)
//     p2: rd A f4-7 ks0+ks1 (8) | STG_B(T+2,h0) | bar+lgkm0 | MFMA f4-7xg0-1
//     p3: STG_A(T+2,h0+h1); VM6 [tail VM0] | bar+lgkm0 | MFMA f4-7 x g2-3
//   B-frags live all 4 phases. vmcnt(6)@p3 proves tile T+1 landed, leaves
//   T+2's 6 in flight (ledger verified incl. prologue & tail).
//   Swizzle (128B rows, 8 chunks): LDS(r,c)=G(r, c^(r&7)); pre-swizzled
//   global source (linear gload dest) + same involution on ds_read offs.
// EPI=1: outH = f16(sg * relu(acc + bias)); simple m/n decode (R2-era).
// EPI=2: XCD-partitioned decode (grid 256): xx=XCD; kh=xx>>2 selects K-half
//   (Aeff=A+kh*khA, Beff=B+kh*khB, P=kh?P1:P0); n0=(xx&3)*256; m0=(lg&31)*256.
//   Epilogue: per-wave LDS bounce -> float4 RMW (p1w -> plain write).
// ---------------------------------------------------------------------------
template <int EPI>
__global__ __launch_bounds__(512, 2) void gemm8p(
    const f16* __restrict__ A, int lda,
    const f16* __restrict__ B, int ldb, int nt,
    long long khA, long long khB,
    const float* __restrict__ bias,
    f16* __restrict__ outH, int ldc,
    float* outP0, float* outP1, int p1w,
    const float* __restrict__ sgate, int expert, int gx) {
  __shared__ alignas(16) f16 lA[4 * 8192];   // 4 half-tile slots x 16KB
  __shared__ alignas(16) f16 lB[4 * 8192];
  const int tid = threadIdx.x;
  const int l = tid & 63, w = tid >> 6;
  const int wr = w >> 2, wc = w & 3;

  // T1 XCD swizzle (grid % 8 == 0 in all launches)
  const int nwg = gridDim.x, cpx = nwg >> 3;
  const int lg = ((int)blockIdx.x & 7) * cpx + ((int)blockIdx.x >> 3);

  int m0, n0;
  const f16* Aeff = A;
  const f16* Beff = B;
  float* P = nullptr;
  bool pw = false;
  if constexpr (EPI == 1) {
    m0 = (lg / gx) * 256; n0 = (lg % gx) * 256;
  } else {
    const int xx = lg >> 5, cc = lg & 31;   // xx = XCD id, grid == 256
    const int kh = xx >> 2;                 // XCD 0-3 -> half 0; 4-7 -> half 1
    n0 = (xx & 3) * 256;                    // one n-tile per XCD
    m0 = cc * 256;
    Aeff = A + (size_t)kh * (size_t)khA;
    Beff = B + (size_t)kh * (size_t)khB;
    P = kh ? outP1 : outP0;
    pw = (p1w != 0);
  }

  // staging: thread -> (row tid>>3, chunk tid&7); source chunk pre-swizzled
  const int srow = tid >> 3;
  const int sxc = (tid & 7) ^ (srow & 7);
  const f16* pA = Aeff + (size_t)(m0 + srow) * lda + sxc * 8;
  const f16* pB = Beff + (size_t)(n0 + srow) * ldb + sxc * 8;
  f16* const dA = lA + w * 512;   // wave-uniform LDS base (+ lane*16B by HW)
  f16* const dB = lB + w * 512;

#define STG_A(slot, h, tk) do { \
    const f16* s_ = pA + (size_t)(h) * 128 * lda + (size_t)(tk) * 64; \
    gload_lds16(s_,            dA + (slot) * 8192); \
    gload_lds16(s_ + 64 * lda, dA + (slot) * 8192 + 4096); \
  } while (0)
#define STG_B(slot, h, tk) do { \
    const f16* s_ = pB + (size_t)(h) * 128 * ldb + (size_t)(tk) * 64; \
    gload_lds16(s_,            dB + (slot) * 8192); \
    gload_lds16(s_ + 64 * ldb, dB + (slot) * 8192 + 4096); \
  } while (0)

  // ds_read fragment offsets (bytes), same xor involution as the source
  const int cg = l >> 4, xr = l & 7;
  const int ok0 = ((cg ^ xr) << 4);
  const int ok1 = (((4 + cg) ^ xr) << 4);
  const char* const baA = (const char*)lA + (l & 15) * 128;
  const char* const baB = (const char*)lB + (wc & 1) * 8192 + (l & 15) * 128;

#define RDA(CA, f, o) (*(const f16x8*)(baA + ((CA) + wr) * 16384 + (f) * 2048 + (o)))
#define RDB(CB, g, o) (*(const f16x8*)(baB + ((CB) + (wc >> 1)) * 16384 + (g) * 2048 + (o)))
#define SYNC() do { __builtin_amdgcn_s_barrier(); \
    asm volatile("s_waitcnt lgkmcnt(0)" ::: "memory"); \
    __builtin_amdgcn_sched_barrier(0); } while (0)
#define ENDPH() do { __builtin_amdgcn_s_setprio(0); \
    __builtin_amdgcn_s_barrier(); } while (0)
#define VM6() do { asm volatile("s_waitcnt vmcnt(6)" ::: "memory"); \
    __builtin_amdgcn_sched_barrier(0); } while (0)
#define VM0() do { asm volatile("s_waitcnt vmcnt(0)" ::: "memory"); \
    __builtin_amdgcn_sched_barrier(0); } while (0)
#define MM(f, g, ar, br) acc[f][g] = MFMAOP(ar, br, acc[f][g])

  f32x4 acc[8][4] = {};
  f16x8 aA0,aA1,aB0,aB1,aC0,aC1,aD0,aD1;   // 4 m-frags x 2 kslices (reused)
  f16x8 b00,b01,b10,b11,b20,b21,b30,b31;   // 4 n-frags x 2 kslices

#define TILEBODY(T, CA, CB, SB1, SB0n, SA0n, SA1n) do { \
    /* phase 0: f0-3 both ks + g0-1 both ks (12 reads) */ \
    aA0 = RDA(CA, 0, ok0); aA1 = RDA(CA, 0, ok1); \
    aB0 = RDA(CA, 1, ok0); aB1 = RDA(CA, 1, ok1); \
    aC0 = RDA(CA, 2, ok0); aC1 = RDA(CA, 2, ok1); \
    aD0 = RDA(CA, 3, ok0); aD1 = RDA(CA, 3, ok1); \
    b00 = RDB(CB, 0, ok0); b01 = RDB(CB, 0, ok1); \
    b10 = RDB(CB, 1, ok0); b11 = RDB(CB, 1, ok1); \
    if ((T) + 1 < nt) STG_B(SB1, 1, (T) + 1); \
    SYNC(); \
    __builtin_amdgcn_s_setprio(1); \
    MM(0,0,aA0,b00); MM(0,1,aA0,b10); MM(1,0,aB0,b00); MM(1,1,aB0,b10); \
    MM(2,0,aC0,b00); MM(2,1,aC0,b10); MM(3,0,aD0,b00); MM(3,1,aD0,b10); \
    MM(0,0,aA1,b01); MM(0,1,aA1,b11); MM(1,0,aB1,b01); MM(1,1,aB1,b11); \
    MM(2,0,aC1,b01); MM(2,1,aC1,b11); MM(3,0,aD1,b01); MM(3,1,aD1,b11); \
    ENDPH(); \
    /* phase 1: g2-3 both ks (4 reads) */ \
    b20 = RDB(CB, 2, ok0); b21 = RDB(CB, 2, ok1); \
    b30 = RDB(CB, 3, ok0); b31 = RDB(CB, 3, ok1); \
    SYNC(); \
    __builtin_amdgcn_s_setprio(1); \
    MM(0,2,aA0,b20); MM(0,3,aA0,b30); MM(1,2,aB0,b20); MM(1,3,aB0,b30); \
    MM(2,2,aC0,b20); MM(2,3,aC0,b30); MM(3,2,aD0,b20); MM(3,3,aD0,b30); \
    MM(0,2,aA1,b21); MM(0,3,aA1,b31); MM(1,2,aB1,b21); MM(1,3,aB1,b31); \
    MM(2,2,aC1,b21); MM(2,3,aC1,b31); MM(3,2,aD1,b21); MM(3,3,aD1,b31); \
    ENDPH(); \
    /* phase 2: f4-7 both ks (8 reads) */ \
    aA0 = RDA(CA, 4, ok0); aA1 = RDA(CA, 4, ok1); \
    aB0 = RDA(CA, 5, ok0); aB1 = RDA(CA, 5, ok1); \
    aC0 = RDA(CA, 6, ok0); aC1 = RDA(CA, 6, ok1); \
    aD0 = RDA(CA, 7, ok0); aD1 = RDA(CA, 7, ok1); \
    if ((T) + 2 < nt) STG_B(SB0n, 0, (T) + 2); \
    SYNC(); \
    __builtin_amdgcn_s_setprio(1); \
    MM(4,0,aA0,b00); MM(4,1,aA0,b10); MM(5,0,aB0,b00); MM(5,1,aB0,b10); \
    MM(6,0,aC0,b00); MM(6,1,aC0,b10); MM(7,0,aD0,b00); MM(7,1,aD0,b10); \
    MM(4,0,aA1,b01); MM(4,1,aA1,b11); MM(5,0,aB1,b01); MM(5,1,aB1,b11); \
    MM(6,0,aC1,b01); MM(6,1,aC1,b11); MM(7,0,aD1,b01); MM(7,1,aD1,b11); \
    ENDPH(); \
    /* phase 3: stage A(T+2); counted vmcnt (tail VM0) */ \
    if ((T) + 2 < nt) { STG_A(SA0n, 0, (T) + 2); STG_A(SA1n, 1, (T) + 2); \
                        VM6(); } \
    else { VM0(); } \
    SYNC(); \
    __builtin_amdgcn_s_setprio(1); \
    MM(4,2,aA0,b20); MM(4,3,aA0,b30); MM(5,2,aB0,b20); MM(5,3,aB0,b30); \
    MM(6,2,aC0,b20); MM(6,3,aC0,b30); MM(7,2,aD0,b20); MM(7,3,aD0,b30); \
    MM(4,2,aA1,b21); MM(4,3,aA1,b31); MM(5,2,aB1,b21); MM(5,3,aB1,b31); \
    MM(6,2,aC1,b21); MM(6,3,aC1,b31); MM(7,2,aD1,b21); MM(7,3,aD1,b31); \
    ENDPH(); \
  } while (0)

  // prologue: tile0 (A0,B0,A1,B1) + tile1 (A0,B0,A1); 14 loads, drain to 6
  STG_A(0, 0, 0); STG_B(0, 0, 0); STG_A(1, 1, 0); STG_B(1, 1, 0);
  STG_A(2, 0, 1); STG_B(2, 0, 1); STG_A(3, 1, 1);
  asm volatile("s_waitcnt vmcnt(6)" ::: "memory");
  __builtin_amdgcn_s_barrier();

  for (int t = 0; t < nt; t += 2) {
    TILEBODY(t,     0, 0, 3, 0, 0, 1);
    TILEBODY(t + 1, 2, 2, 1, 2, 2, 3);
  }
  asm volatile("s_waitcnt vmcnt(0)" ::: "memory");

  // epilogue
  if constexpr (EPI == 1) {
#pragma unroll
    for (int mi = 0; mi < 8; ++mi)
#pragma unroll
      for (int r = 0; r < 4; ++r) {
        const int row = m0 + wr * 128 + mi * 16 + (l >> 4) * 4 + r;
        const float sg = sgate[(size_t)row * 8 + expert];
#pragma unroll
        for (int ni = 0; ni < 4; ++ni) {
          const int col = n0 + wc * 64 + ni * 16 + (l & 15);
          const float v = acc[mi][ni][r] + bias[col];
          outH[(size_t)row * ldc + col] = (f16)(fmaxf(v, 0.0f) * sg);
        }
      }
  } else {
    // float4 LDS-bounce RMW epilogue; LDS free after final ENDPH barrier.
    // Wave-private scratch, in-order DS pipe -> no barriers needed.
    float* const scr = (w < 4) ? (float*)lA + w * 4096
                               : (float*)lB + (w - 4) * 4096;
    const int hl = l >> 4, ll = l & 15;
#pragma unroll
    for (int p = 0; p < 2; ++p) {
#pragma unroll
      for (int mi4 = 0; mi4 < 4; ++mi4)
#pragma unroll
        for (int r = 0; r < 4; ++r) {
          const int rowl = mi4 * 16 + hl * 4 + r;
#pragma unroll
          for (int ni = 0; ni < 4; ++ni)
            scr[rowl * 64 + ni * 16 + ll] = acc[p * 4 + mi4][ni][r];
        }
#pragma unroll
      for (int i = 0; i < 16; ++i) {
        const int rowl = hl + i * 4;
        f32x4 v = *(const f32x4*)(scr + rowl * 64 + ll * 4);
        const int row = m0 + wr * 128 + p * 64 + rowl;
        const int col = n0 + wc * 64 + ll * 4;
        f32x4* gp = (f32x4*)(P + (size_t)row * 1024 + col);
        if (!pw) {
          const f32x4 g = *gp;
          v[0] += g[0]; v[1] += g[1]; v[2] += g[2]; v[3] += g[3];
        }
        *gp = v;
      }
    }
  }
#undef STG_A
#undef STG_B
#undef RDA
#undef RDB
#undef SYNC
#undef ENDPH
#undef VM6
#undef VM0
#undef MM
#undef TILEBODY
}

// out = [p0 + p1 +] sum_e sg[n,e]*b2[e,:]   (float4-vectorized)
// NOTE: p0 may alias out -> no __restrict__ on p0/out.
template <bool WITHP>
__global__ void finalize_out(const float* p0,
                             const float* __restrict__ p1,
                             const float* __restrict__ sgate,
                             const float* __restrict__ b2,
                             float* out) {
  const int i = blockIdx.x * 256 + threadIdx.x;   // float4 index, 2M total
  const int n = i >> 8, c4 = i & 255;
  float4 a = make_float4(0.f, 0.f, 0.f, 0.f);
  if constexpr (WITHP) {
    const float4 u = ((const float4*)p0)[i];
    const float4 v = ((const float4*)p1)[i];
    a.x = u.x + v.x; a.y = u.y + v.y; a.z = u.z + v.z; a.w = u.w + v.w;
  }
  const float* sg = sgate + (size_t)n * 8;
#pragma unroll
  for (int e = 0; e < 8; ++e) {
    const float s = sg[e];
    const float4 bv = ((const float4*)(b2 + (size_t)e * 1024))[c4];
    a.x += s * bv.x; a.y += s * bv.y; a.z += s * bv.z; a.w += s * bv.w;
  }
  ((float4*)out)[i] = a;
}

extern "C" void kernel_launch(void* const* d_in, const int* in_sizes, int n_in,
                              void* d_out, int out_size, void* d_ws, size_t ws_size,
                              hipStream_t stream) {
  const float* x  = (const float*)d_in[0];
  const float* gw = (const float*)d_in[1];
  const float* gb = (const float*)d_in[2];
  const float* w1 = (const float*)d_in[3];
  const float* b1 = (const float*)d_in[4];
  const float* w2 = (const float*)d_in[5];
  const float* b2 = (const float*)d_in[6];
  float* out = (float*)d_out;

  char* ws = (char*)d_ws;
  float* sgate = (float*)(ws + OFF_SGATE);
  f16* xh  = (f16*)(ws + OFF_XH);
  f16* w1t = (f16*)(ws + OFF_W1T);
  f16* w2t = (f16*)(ws + OFF_W2T);
  float* p1 = (float*)(ws + OFF_P1);
  f16* hh  = (f16*)(ws + OFF_HH);

  // expert-group fold width: NE=2 keeps concurrent GEMM2 A-set at 128MB
  // (L3-shareable across the 4 XCDs per K-half).
  const int NE = (ws_size >= NEED_NE2) ? 2 : 1;
  const int ngrp = NEXP / NE;

  gate_kernel<<<NROWS / 4, 256, 0, stream>>>(x, gw, gb, sgate);
  cvt_x_kernel<<<(NROWS * DIN) / (256 * 4), 256, 0, stream>>>(x, xh);
  transpose_cvt<<<dim3(DHID / 32, DIN / 32, NEXP), dim3(32, 8), 0, stream>>>(w1, w1t, DIN, DHID);
  transpose_cvt<<<dim3(DOUT / 32, DHID / 32, NEXP), dim3(32, 8), 0, stream>>>(w2, w2t, DHID, DOUT);

  const long long khA = (long long)NE * 2048;                 // A K-half cols
  const long long khB = (NE == 2) ? (long long)DOUT * DHID    // expert stride
                                  : 2048LL;                   // within-expert
  const int nt2 = NE * 32;                                    // K-half / 64
  for (int g = 0; g < ngrp; ++g) {
    for (int ei = 0; ei < NE; ++ei) {
      const int e = g * NE + ei;
      gemm8p<1><<<512, 512, 0, stream>>>(
          xh, DIN, w1t + (size_t)e * DHID * DIN, DIN, DIN / 64,
          0, 0,
          b1 + (size_t)e * DHID, hh + (size_t)ei * DHID, NE * DHID,
          nullptr, nullptr, 0, sgate, e, DHID / 256);
    }
    gemm8p<2><<<256, 512, 0, stream>>>(
        hh, NE * DHID, w2t + (size_t)g * NE * DOUT * DHID, DHID, nt2,
        khA, khB,
        nullptr, nullptr, 0, out, p1, (g == 0) ? 1 : 0, nullptr, 0, 0);
  }
  finalize_out<true><<<(NROWS * DOUT) / (256 * 4), 256, 0, stream>>>(
      out, p1, sgate, b2, out);
}

// Round 10
// 1357.527 us; speedup vs baseline: 1.5035x; 1.0480x over previous
//
#include <hip/hip_runtime.h>
#include <hip/hip_bf16.h>
#include <cmath>

// ---------------------------------------------------------------------------
// MoE "pure field": gate(softmax@T=e, top-5/8, renorm, sign) + dense 2-layer
// FFN over all experts, accumulated with signed gate weights.
//   N=8192, D_IN=1024, D_HID=4096, D_OUT=1024, E=8, k=5
// Round 13: GEMM2 A-reuse decode fix on the R12 base (session best 1422us).
//   Old EPI=2 decode gave each XCD one n-tile -> each of the 4 n-XCDs
//   streamed the whole 64MB A-half from HBM (FETCH 303MB vs 208 ideal,
//   every A load ~900cy). New decode: each XCD owns 8 m-tiles x ALL 4
//   n-tiles of one K-half; the 4 co-resident n-blocks of an m-group share
//   their A-panel via the XCD's L2 (A fetched once; B 8MB L3-backed).
//   Everything else byte-identical to R12.
// ---------------------------------------------------------------------------

typedef _Float16 f16;
typedef _Float16 f16x8 __attribute__((ext_vector_type(8)));
typedef _Float16 f16x4 __attribute__((ext_vector_type(4)));
typedef float f32x4 __attribute__((ext_vector_type(4)));

#define NROWS 8192
#define DIN   1024
#define DHID  4096
#define DOUT  1024
#define NEXP  8

// workspace layout (bytes)
#define OFF_SGATE 0u
#define OFF_XH    262144u          // xh: 8192x1024 f16 = 16MB
#define OFF_W1T   17039360u        // w1t: 8x4096x1024 f16 = 64MB
#define OFF_W2T   84148224u        // w2t: 8x1024x4096 f16 = 64MB
#define OFF_P1    151257088u       // P1 partial f32 = 32MB
#define OFF_HH    184811520u       // hh group buffer: NE x 64MB
#define NEED_NE2  319029248ull

__device__ __forceinline__ void gload_lds16(const void* gsrc, void* ldsdst) {
  __builtin_amdgcn_global_load_lds(
      (const __attribute__((address_space(1))) unsigned int*)gsrc,
      (__attribute__((address_space(3))) unsigned int*)ldsdst, 16, 0, 0);
}

// ---------------------------------------------------------------------------
// Gate (proven form).
// ---------------------------------------------------------------------------
__global__ void gate_kernel(const float* __restrict__ x,
                            const float* __restrict__ gw,
                            const float* __restrict__ gb,
                            float* __restrict__ sgate) {
  const int row = blockIdx.x * 4 + (threadIdx.x >> 6);
  const int l = threadIdx.x & 63;
  const float* xr = x + (size_t)row * DIN;
  float acc[8] = {0.f,0.f,0.f,0.f,0.f,0.f,0.f,0.f};
#pragma unroll
  for (int j = 0; j < 16; ++j) {
    const int k = l + 64 * j;
    const float xv = xr[k];
    const float4 g0 = *(const float4*)(gw + (size_t)k * 8);
    const float4 g1 = *(const float4*)(gw + (size_t)k * 8 + 4);
    acc[0] += xv * g0.x; acc[1] += xv * g0.y; acc[2] += xv * g0.z; acc[3] += xv * g0.w;
    acc[4] += xv * g1.x; acc[5] += xv * g1.y; acc[6] += xv * g1.z; acc[7] += xv * g1.w;
  }
#pragma unroll
  for (int off = 32; off > 0; off >>= 1) {
#pragma unroll
    for (int e = 0; e < 8; ++e) acc[e] += __shfl_xor(acc[e], off, 64);
  }
  if (l == 0) {
    const float invT = 0.36787944117144233f;
    float p[8]; float mx = -1e30f;
#pragma unroll
    for (int e = 0; e < 8; ++e) { p[e] = (acc[e] + gb[e]) * invT; mx = fmaxf(mx, p[e]); }
    float S = 0.f;
#pragma unroll
    for (int e = 0; e < 8; ++e) { p[e] = expf(p[e] - mx); S += p[e]; }
    const float inv = 1.0f / S;
#pragma unroll
    for (int e = 0; e < 8; ++e) p[e] *= inv;
    bool keep[8] = {true,true,true,true,true,true,true,true};
    for (int t = 0; t < 3; ++t) {
      float pmin = 1e30f; int mi = -1;
      for (int e = 0; e < 8; ++e)
        if (keep[e] && (p[e] < pmin || (p[e] == pmin && e > mi))) { pmin = p[e]; mi = e; }
      keep[mi] = false;
    }
    float wsum = 0.f;
#pragma unroll
    for (int e = 0; e < 8; ++e) if (keep[e]) wsum += p[e];
    const float rinv = 1.0f / (wsum + 1e-8f);
#pragma unroll
    for (int e = 0; e < 8; ++e) {
      const float wv = keep[e] ? p[e] * rinv : 0.0f;
      sgate[(size_t)row * 8 + e] = (e < 4) ? wv : -wv;
    }
  }
}

__global__ void cvt_x_kernel(const float* __restrict__ x, f16* __restrict__ xh) {
  const size_t i = ((size_t)blockIdx.x * blockDim.x + threadIdx.x) * 4;
  const float4 v = *(const float4*)(x + i);
  f16x4 o = { (f16)v.x, (f16)v.y, (f16)v.z, (f16)v.w };
  *(f16x4*)(xh + i) = o;
}

// in f32 [E][R][C] -> out fp16 [E][C][R]
__global__ void transpose_cvt(const float* __restrict__ in, f16* __restrict__ out,
                              int R, int C) {
  __shared__ float tile[32][33];
  const int e = blockIdx.z;
  const float* ine = in + (size_t)e * R * C;
  f16* oute = out + (size_t)e * R * C;
  const int c0 = blockIdx.x * 32, r0 = blockIdx.y * 32;
  const int tx = threadIdx.x, ty = threadIdx.y;
#pragma unroll
  for (int i = 0; i < 4; ++i)
    tile[ty + i * 8][tx] = ine[(size_t)(r0 + ty + i * 8) * C + c0 + tx];
  __syncthreads();
#pragma unroll
  for (int i = 0; i < 4; ++i)
    oute[(size_t)(c0 + ty + i * 8) * R + r0 + tx] = (f16)tile[tx][ty + i * 8];
}

#define MFMAOP(a_, b_, c_) __builtin_amdgcn_mfma_f32_16x16x32_f16(a_, b_, c_, 0, 0, 0)

// ---------------------------------------------------------------------------
// gemm8p: 256x256 BK=64, 4 phases/tile, 4 half-tile LDS slots per operand.
//   R1/R2-era phase partition:
//     p0: rd A f0-3 ks0+ks1 (8) + B g0-1 ks0+ks1 (4) | STG_B(T+1,h1) |
//         bar+lgkm0 | MFMA f0-3 x g0-1 x both ks (16)
//     p1: rd B g2-3 ks0+ks1 (4) | bar+lgkm0 | MFMA f0-3 x g2-3 (16)
//     p2: rd A f4-7 ks0+ks1 (8) | STG_B(T+2,h0) | bar+lgkm0 | MFMA f4-7xg0-1
//     p3: STG_A(T+2,h0+h1); VM6 [tail VM0] | bar+lgkm0 | MFMA f4-7 x g2-3
//   B-frags live all 4 phases. vmcnt(6)@p3 proves tile T+1 landed, leaves
//   T+2's 6 in flight (ledger verified incl. prologue & tail).
//   Swizzle (128B rows, 8 chunks): LDS(r,c)=G(r, c^(r&7)); pre-swizzled
//   global source (linear gload dest) + same involution on ds_read offs.
// EPI=1: outH = f16(sg * relu(acc + bias)); simple m/n decode.
// EPI=2 (R13): m-partitioned XCD decode (grid 256): XCD xx owns 8 m-tiles
//   x all 4 n-tiles of K-half kh=xx>>2. The 4 co-resident n-blocks of an
//   m-group share the A-panel via L2 -> A HBM-fetched once (was 4x).
//   Aeff=A+kh*khA, Beff=B+kh*khB, P=kh?P1:P0.
//   Epilogue: per-wave LDS bounce -> float4 RMW (p1w -> plain write).
// ---------------------------------------------------------------------------
template <int EPI>
__global__ __launch_bounds__(512, 2) void gemm8p(
    const f16* __restrict__ A, int lda,
    const f16* __restrict__ B, int ldb, int nt,
    long long khA, long long khB,
    const float* __restrict__ bias,
    f16* __restrict__ outH, int ldc,
    float* outP0, float* outP1, int p1w,
    const float* __restrict__ sgate, int expert, int gx) {
  __shared__ alignas(16) f16 lA[4 * 8192];   // 4 half-tile slots x 16KB
  __shared__ alignas(16) f16 lB[4 * 8192];
  const int tid = threadIdx.x;
  const int l = tid & 63, w = tid >> 6;
  const int wr = w >> 2, wc = w & 3;

  // T1 XCD swizzle (grid % 8 == 0 in all launches)
  const int nwg = gridDim.x, cpx = nwg >> 3;
  const int lg = ((int)blockIdx.x & 7) * cpx + ((int)blockIdx.x >> 3);

  int m0, n0;
  const f16* Aeff = A;
  const f16* Beff = B;
  float* P = nullptr;
  bool pw = false;
  if constexpr (EPI == 1) {
    m0 = (lg / gx) * 256; n0 = (lg % gx) * 256;
  } else {
    // m-partitioned XCD decode (grid 256): xx = XCD id in [0,8).
    // Each XCD: K-half kh = xx>>2; m-tiles [(xx&3)*8, +8); all 4 n-tiles.
    // Co-resident n-blocks of an m-group share A-panels through L2.
    const int xx = lg >> 5, cc = lg & 31;
    const int kh = xx >> 2;
    n0 = (cc & 3) * 256;
    m0 = (((xx & 3) << 3) + (cc >> 2)) * 256;
    Aeff = A + (size_t)kh * (size_t)khA;
    Beff = B + (size_t)kh * (size_t)khB;
    P = kh ? outP1 : outP0;
    pw = (p1w != 0);
  }

  // staging: thread -> (row tid>>3, chunk tid&7); source chunk pre-swizzled
  const int srow = tid >> 3;
  const int sxc = (tid & 7) ^ (srow & 7);
  const f16* pA = Aeff + (size_t)(m0 + srow) * lda + sxc * 8;
  const f16* pB = Beff + (size_t)(n0 + srow) * ldb + sxc * 8;
  f16* const dA = lA + w * 512;   // wave-uniform LDS base (+ lane*16B by HW)
  f16* const dB = lB + w * 512;

#define STG_A(slot, h, tk) do { \
    const f16* s_ = pA + (size_t)(h) * 128 * lda + (size_t)(tk) * 64; \
    gload_lds16(s_,            dA + (slot) * 8192); \
    gload_lds16(s_ + 64 * lda, dA + (slot) * 8192 + 4096); \
  } while (0)
#define STG_B(slot, h, tk) do { \
    const f16* s_ = pB + (size_t)(h) * 128 * ldb + (size_t)(tk) * 64; \
    gload_lds16(s_,            dB + (slot) * 8192); \
    gload_lds16(s_ + 64 * ldb, dB + (slot) * 8192 + 4096); \
  } while (0)

  // ds_read fragment offsets (bytes), same xor involution as the source
  const int cg = l >> 4, xr = l & 7;
  const int ok0 = ((cg ^ xr) << 4);
  const int ok1 = (((4 + cg) ^ xr) << 4);
  const char* const baA = (const char*)lA + (l & 15) * 128;
  const char* const baB = (const char*)lB + (wc & 1) * 8192 + (l & 15) * 128;

#define RDA(CA, f, o) (*(const f16x8*)(baA + ((CA) + wr) * 16384 + (f) * 2048 + (o)))
#define RDB(CB, g, o) (*(const f16x8*)(baB + ((CB) + (wc >> 1)) * 16384 + (g) * 2048 + (o)))
#define SYNC() do { __builtin_amdgcn_s_barrier(); \
    asm volatile("s_waitcnt lgkmcnt(0)" ::: "memory"); \
    __builtin_amdgcn_sched_barrier(0); } while (0)
#define ENDPH() do { __builtin_amdgcn_s_setprio(0); \
    __builtin_amdgcn_s_barrier(); } while (0)
#define VM6() do { asm volatile("s_waitcnt vmcnt(6)" ::: "memory"); \
    __builtin_amdgcn_sched_barrier(0); } while (0)
#define VM0() do { asm volatile("s_waitcnt vmcnt(0)" ::: "memory"); \
    __builtin_amdgcn_sched_barrier(0); } while (0)
#define MM(f, g, ar, br) acc[f][g] = MFMAOP(ar, br, acc[f][g])

  f32x4 acc[8][4] = {};
  f16x8 aA0,aA1,aB0,aB1,aC0,aC1,aD0,aD1;   // 4 m-frags x 2 kslices (reused)
  f16x8 b00,b01,b10,b11,b20,b21,b30,b31;   // 4 n-frags x 2 kslices

#define TILEBODY(T, CA, CB, SB1, SB0n, SA0n, SA1n) do { \
    /* phase 0: f0-3 both ks + g0-1 both ks (12 reads) */ \
    aA0 = RDA(CA, 0, ok0); aA1 = RDA(CA, 0, ok1); \
    aB0 = RDA(CA, 1, ok0); aB1 = RDA(CA, 1, ok1); \
    aC0 = RDA(CA, 2, ok0); aC1 = RDA(CA, 2, ok1); \
    aD0 = RDA(CA, 3, ok0); aD1 = RDA(CA, 3, ok1); \
    b00 = RDB(CB, 0, ok0); b01 = RDB(CB, 0, ok1); \
    b10 = RDB(CB, 1, ok0); b11 = RDB(CB, 1, ok1); \
    if ((T) + 1 < nt) STG_B(SB1, 1, (T) + 1); \
    SYNC(); \
    __builtin_amdgcn_s_setprio(1); \
    MM(0,0,aA0,b00); MM(0,1,aA0,b10); MM(1,0,aB0,b00); MM(1,1,aB0,b10); \
    MM(2,0,aC0,b00); MM(2,1,aC0,b10); MM(3,0,aD0,b00); MM(3,1,aD0,b10); \
    MM(0,0,aA1,b01); MM(0,1,aA1,b11); MM(1,0,aB1,b01); MM(1,1,aB1,b11); \
    MM(2,0,aC1,b01); MM(2,1,aC1,b11); MM(3,0,aD1,b01); MM(3,1,aD1,b11); \
    ENDPH(); \
    /* phase 1: g2-3 both ks (4 reads) */ \
    b20 = RDB(CB, 2, ok0); b21 = RDB(CB, 2, ok1); \
    b30 = RDB(CB, 3, ok0); b31 = RDB(CB, 3, ok1); \
    SYNC(); \
    __builtin_amdgcn_s_setprio(1); \
    MM(0,2,aA0,b20); MM(0,3,aA0,b30); MM(1,2,aB0,b20); MM(1,3,aB0,b30); \
    MM(2,2,aC0,b20); MM(2,3,aC0,b30); MM(3,2,aD0,b20); MM(3,3,aD0,b30); \
    MM(0,2,aA1,b21); MM(0,3,aA1,b31); MM(1,2,aB1,b21); MM(1,3,aB1,b31); \
    MM(2,2,aC1,b21); MM(2,3,aC1,b31); MM(3,2,aD1,b21); MM(3,3,aD1,b31); \
    ENDPH(); \
    /* phase 2: f4-7 both ks (8 reads) */ \
    aA0 = RDA(CA, 4, ok0); aA1 = RDA(CA, 4, ok1); \
    aB0 = RDA(CA, 5, ok0); aB1 = RDA(CA, 5, ok1); \
    aC0 = RDA(CA, 6, ok0); aC1 = RDA(CA, 6, ok1); \
    aD0 = RDA(CA, 7, ok0); aD1 = RDA(CA, 7, ok1); \
    if ((T) + 2 < nt) STG_B(SB0n, 0, (T) + 2); \
    SYNC(); \
    __builtin_amdgcn_s_setprio(1); \
    MM(4,0,aA0,b00); MM(4,1,aA0,b10); MM(5,0,aB0,b00); MM(5,1,aB0,b10); \
    MM(6,0,aC0,b00); MM(6,1,aC0,b10); MM(7,0,aD0,b00); MM(7,1,aD0,b10); \
    MM(4,0,aA1,b01); MM(4,1,aA1,b11); MM(5,0,aB1,b01); MM(5,1,aB1,b11); \
    MM(6,0,aC1,b01); MM(6,1,aC1,b11); MM(7,0,aD1,b01); MM(7,1,aD1,b11); \
    ENDPH(); \
    /* phase 3: stage A(T+2); counted vmcnt (tail VM0) */ \
    if ((T) + 2 < nt) { STG_A(SA0n, 0, (T) + 2); STG_A(SA1n, 1, (T) + 2); \
                        VM6(); } \
    else { VM0(); } \
    SYNC(); \
    __builtin_amdgcn_s_setprio(1); \
    MM(4,2,aA0,b20); MM(4,3,aA0,b30); MM(5,2,aB0,b20); MM(5,3,aB0,b30); \
    MM(6,2,aC0,b20); MM(6,3,aC0,b30); MM(7,2,aD0,b20); MM(7,3,aD0,b30); \
    MM(4,2,aA1,b21); MM(4,3,aA1,b31); MM(5,2,aB1,b21); MM(5,3,aB1,b31); \
    MM(6,2,aC1,b21); MM(6,3,aC1,b31); MM(7,2,aD1,b21); MM(7,3,aD1,b31); \
    ENDPH(); \
  } while (0)

  // prologue: tile0 (A0,B0,A1,B1) + tile1 (A0,B0,A1); 14 loads, drain to 6
  STG_A(0, 0, 0); STG_B(0, 0, 0); STG_A(1, 1, 0); STG_B(1, 1, 0);
  STG_A(2, 0, 1); STG_B(2, 0, 1); STG_A(3, 1, 1);
  asm volatile("s_waitcnt vmcnt(6)" ::: "memory");
  __builtin_amdgcn_s_barrier();

  for (int t = 0; t < nt; t += 2) {
    TILEBODY(t,     0, 0, 3, 0, 0, 1);
    TILEBODY(t + 1, 2, 2, 1, 2, 2, 3);
  }
  asm volatile("s_waitcnt vmcnt(0)" ::: "memory");

  // epilogue
  if constexpr (EPI == 1) {
#pragma unroll
    for (int mi = 0; mi < 8; ++mi)
#pragma unroll
      for (int r = 0; r < 4; ++r) {
        const int row = m0 + wr * 128 + mi * 16 + (l >> 4) * 4 + r;
        const float sg = sgate[(size_t)row * 8 + expert];
#pragma unroll
        for (int ni = 0; ni < 4; ++ni) {
          const int col = n0 + wc * 64 + ni * 16 + (l & 15);
          const float v = acc[mi][ni][r] + bias[col];
          outH[(size_t)row * ldc + col] = (f16)(fmaxf(v, 0.0f) * sg);
        }
      }
  } else {
    // float4 LDS-bounce RMW epilogue; LDS free after final ENDPH barrier.
    // Wave-private scratch, in-order DS pipe -> no barriers needed.
    float* const scr = (w < 4) ? (float*)lA + w * 4096
                               : (float*)lB + (w - 4) * 4096;
    const int hl = l >> 4, ll = l & 15;
#pragma unroll
    for (int p = 0; p < 2; ++p) {
#pragma unroll
      for (int mi4 = 0; mi4 < 4; ++mi4)
#pragma unroll
        for (int r = 0; r < 4; ++r) {
          const int rowl = mi4 * 16 + hl * 4 + r;
#pragma unroll
          for (int ni = 0; ni < 4; ++ni)
            scr[rowl * 64 + ni * 16 + ll] = acc[p * 4 + mi4][ni][r];
        }
#pragma unroll
      for (int i = 0; i < 16; ++i) {
        const int rowl = hl + i * 4;
        f32x4 v = *(const f32x4*)(scr + rowl * 64 + ll * 4);
        const int row = m0 + wr * 128 + p * 64 + rowl;
        const int col = n0 + wc * 64 + ll * 4;
        f32x4* gp = (f32x4*)(P + (size_t)row * 1024 + col);
        if (!pw) {
          const f32x4 g = *gp;
          v[0] += g[0]; v[1] += g[1]; v[2] += g[2]; v[3] += g[3];
        }
        *gp = v;
      }
    }
  }
#undef STG_A
#undef STG_B
#undef RDA
#undef RDB
#undef SYNC
#undef ENDPH
#undef VM6
#undef VM0
#undef MM
#undef TILEBODY
}

// out = [p0 + p1 +] sum_e sg[n,e]*b2[e,:]   (float4-vectorized)
// NOTE: p0 may alias out -> no __restrict__ on p0/out.
template <bool WITHP>
__global__ void finalize_out(const float* p0,
                             const float* __restrict__ p1,
                             const float* __restrict__ sgate,
                             const float* __restrict__ b2,
                             float* out) {
  const int i = blockIdx.x * 256 + threadIdx.x;   // float4 index, 2M total
  const int n = i >> 8, c4 = i & 255;
  float4 a = make_float4(0.f, 0.f, 0.f, 0.f);
  if constexpr (WITHP) {
    const float4 u = ((const float4*)p0)[i];
    const float4 v = ((const float4*)p1)[i];
    a.x = u.x + v.x; a.y = u.y + v.y; a.z = u.z + v.z; a.w = u.w + v.w;
  }
  const float* sg = sgate + (size_t)n * 8;
#pragma unroll
  for (int e = 0; e < 8; ++e) {
    const float s = sg[e];
    const float4 bv = ((const float4*)(b2 + (size_t)e * 1024))[c4];
    a.x += s * bv.x; a.y += s * bv.y; a.z += s * bv.z; a.w += s * bv.w;
  }
  ((float4*)out)[i] = a;
}

extern "C" void kernel_launch(void* const* d_in, const int* in_sizes, int n_in,
                              void* d_out, int out_size, void* d_ws, size_t ws_size,
                              hipStream_t stream) {
  const float* x  = (const float*)d_in[0];
  const float* gw = (const float*)d_in[1];
  const float* gb = (const float*)d_in[2];
  const float* w1 = (const float*)d_in[3];
  const float* b1 = (const float*)d_in[4];
  const float* w2 = (const float*)d_in[5];
  const float* b2 = (const float*)d_in[6];
  float* out = (float*)d_out;

  char* ws = (char*)d_ws;
  float* sgate = (float*)(ws + OFF_SGATE);
  f16* xh  = (f16*)(ws + OFF_XH);
  f16* w1t = (f16*)(ws + OFF_W1T);
  f16* w2t = (f16*)(ws + OFF_W2T);
  float* p1 = (float*)(ws + OFF_P1);
  f16* hh  = (f16*)(ws + OFF_HH);

  // expert-group fold width: NE=2 keeps concurrent GEMM2 A-set at 128MB
  // (L3-shareable); NE=1 = proven fallback.
  const int NE = (ws_size >= NEED_NE2) ? 2 : 1;
  const int ngrp = NEXP / NE;

  gate_kernel<<<NROWS / 4, 256, 0, stream>>>(x, gw, gb, sgate);
  cvt_x_kernel<<<(NROWS * DIN) / (256 * 4), 256, 0, stream>>>(x, xh);
  transpose_cvt<<<dim3(DHID / 32, DIN / 32, NEXP), dim3(32, 8), 0, stream>>>(w1, w1t, DIN, DHID);
  transpose_cvt<<<dim3(DOUT / 32, DHID / 32, NEXP), dim3(32, 8), 0, stream>>>(w2, w2t, DHID, DOUT);

  const long long khA = (long long)NE * 2048;                 // A K-half cols
  const long long khB = (NE == 2) ? (long long)DOUT * DHID    // expert stride
                                  : 2048LL;                   // within-expert
  const int nt2 = NE * 32;                                    // K-half / 64
  for (int g = 0; g < ngrp; ++g) {
    for (int ei = 0; ei < NE; ++ei) {
      const int e = g * NE + ei;
      gemm8p<1><<<512, 512, 0, stream>>>(
          xh, DIN, w1t + (size_t)e * DHID * DIN, DIN, DIN / 64,
          0, 0,
          b1 + (size_t)e * DHID, hh + (size_t)ei * DHID, NE * DHID,
          nullptr, nullptr, 0, sgate, e, DHID / 256);
    }
    gemm8p<2><<<256, 512, 0, stream>>>(
        hh, NE * DHID, w2t + (size_t)g * NE * DOUT * DHID, DHID, nt2,
        khA, khB,
        nullptr, nullptr, 0, out, p1, (g == 0) ? 1 : 0, nullptr, 0, 0);
  }
  finalize_out<true><<<(NROWS * DOUT) / (256 * 4), 256, 0, stream>>>(
      out, p1, sgate, b2, out);
}